// Round 1
// baseline (647.429 us; speedup 1.0000x reference)
//
#include <hip/hip_runtime.h>
#include <hip/hip_bf16.h>
#include <float.h>
#include <stdint.h>

// Problem constants
#define NB   64      // batch / num graphs
#define CD   128     // channels / dims
#define OUTD 256
#define NNODE 20000
#define NEDGE 640000

typedef __bf16 bf16x8 __attribute__((ext_vector_type(8)));
typedef float  f32x4  __attribute__((ext_vector_type(4)));

__device__ inline void gl_lds16(const void* g, void* l) {
  __builtin_amdgcn_global_load_lds(
      (const __attribute__((address_space(1))) void*)g,
      (__attribute__((address_space(3))) void*)l, 16, 0, 0);
}

// float atomic max via signed/unsigned int monotonic trick (works for mixed signs)
__device__ inline void atomicMaxF(float* addr, float val) {
  if (val >= 0.f) atomicMax((int*)addr, __float_as_int(val));
  else            atomicMin((unsigned int*)addr, __float_as_uint(val));
}

// ---------------- init: pooled buffers (-FLT_MAX), CSR counters (=0), SN scratch (=0) ----------------
// sn_scratch layout: [0..1151]=v0, [1152..1663]=v1, [1664..1791]=v2, [1792..1795]=ss
__global__ void k_init(float* __restrict__ pooled_v, float* __restrict__ pooled_t,
                       int* __restrict__ cnt, int* __restrict__ fill,
                       float* __restrict__ sn_scratch) {
  const int i = blockIdx.x * 256 + threadIdx.x;   // grid covers 32768
  if (i < NB * CD * 4) pooled_v[i] = -FLT_MAX;
  if (i < NB * CD)     pooled_t[i] = -FLT_MAX;
  if (i < NNODE)       { cnt[i] = 0; fill[i] = 0; }
  if (i < 1796)        sn_scratch[i] = 0.0f;
}

// ---------------- SN stage 1: v = W^T u, 32-row chunks, coalesced, atomicAdd per column ----------------
__global__ __launch_bounds__(256) void k_sn_v(const float* __restrict__ conv_w, const float* __restrict__ conv_u,
                                              const float* __restrict__ fcv_w,  const float* __restrict__ fcv_u,
                                              const float* __restrict__ fct_w,  const float* __restrict__ fct_u,
                                              float* __restrict__ sn) {
  const int bb = blockIdx.x;       // 0..19
  const float* W; const float* u; float* v; int C; int r0;
  if (bb < 4)       { W = conv_w; u = conv_u; v = sn;        C = 1152; r0 = bb * 32; }
  else if (bb < 12) { W = fcv_w;  u = fcv_u;  v = sn + 1152; C = 512;  r0 = (bb - 4) * 32; }
  else              { W = fct_w;  u = fct_u;  v = sn + 1664; C = 128;  r0 = (bb - 12) * 32; }
  const int tid = threadIdx.x;
  float acc[5] = {0.f, 0.f, 0.f, 0.f, 0.f};
  for (int i = r0; i < r0 + 32; ++i) {
    const float ui = u[i];
    const float* row = W + (size_t)i * C;
    #pragma unroll
    for (int t = 0; t < 5; ++t) {
      const int j = tid + t * 256;
      if (j < C) acc[t] += ui * row[j];
    }
  }
  #pragma unroll
  for (int t = 0; t < 5; ++t) {
    const int j = tid + t * 256;
    if (j < C) atomicAdd(&v[j], acc[t]);
  }
}

// ---------------- SN stage 2: ss[m] = ||W v||^2, one wave per row ----------------
__global__ __launch_bounds__(256) void k_sn_w(const float* __restrict__ conv_w,
                                              const float* __restrict__ fcv_w,
                                              const float* __restrict__ fct_w,
                                              float* __restrict__ sn) {
  const int gw = blockIdx.x * 4 + (threadIdx.x >> 6);   // global wave id, 0..639
  const int lane = threadIdx.x & 63;
  const float* W; const float* v; int C, m, row;
  if (gw < 128)      { W = conv_w; v = sn;        C = 1152; m = 0; row = gw; }
  else if (gw < 384) { W = fcv_w;  v = sn + 1152; C = 512;  m = 1; row = gw - 128; }
  else               { W = fct_w;  v = sn + 1664; C = 128;  m = 2; row = gw - 384; }
  const float* wr = W + (size_t)row * C;
  float y = 0.f;
  for (int c = lane; c < C; c += 64) y += wr[c] * v[c];
  #pragma unroll
  for (int s = 32; s > 0; s >>= 1) y += __shfl_xor(y, s, 64);
  if (lane == 0) atomicAdd(&sn[1792 + m], y * y);
}

// ---------------- SN stage 3: inv_sigma[m] = (||v||+eps)/||Wv|| ----------------
__global__ __launch_bounds__(256) void k_sn_fin(const float* __restrict__ sn, float* __restrict__ inv_sigma) {
  __shared__ float red[256];
  const int tid = threadIdx.x;
  const int off[4] = {0, 1152, 1664, 1792};
  for (int m = 0; m < 3; ++m) {
    const int C = off[m + 1] - off[m];
    float ss = 0.f;
    for (int j = tid; j < C; j += 256) { const float a = sn[off[m] + j]; ss += a * a; }
    red[tid] = ss; __syncthreads();
    for (int s = 128; s > 0; s >>= 1) { if (tid < s) red[tid] += red[tid + s]; __syncthreads(); }
    if (tid == 0) inv_sigma[m] = (sqrtf(red[0]) + 1e-12f) / sqrtf(sn[1792 + m]);
    __syncthreads();
  }
}

// ---------------- pack conv weights into staging-coalesced frag order ----------------
// Bt2[tap(9)][halfk(2)][sub(8)][n(128)][c8(8)] = conv_w[n][ci=hk*64+s*8+j][tap] / sigma
__global__ void k_pack(const float* __restrict__ conv_w, const float* __restrict__ inv_sigma,
                       __hip_bfloat16* __restrict__ Bt2) {
  const int t = blockIdx.x * 256 + threadIdx.x;
  if (t >= 147456) return;
  const int j = t & 7, n = (t >> 3) & 127, s = (t >> 10) & 7, hk = (t >> 13) & 1, tap = t >> 14;
  const int ci = hk * 64 + s * 8 + j;
  Bt2[t] = __float2bfloat16(conv_w[n * 1152 + ci * 9 + tap] * inv_sigma[0]);
}

// ---------------- NCHW f32 -> tiled bf16: visT2[b][y][g=c/8][x(64)][c8(8)] ----------------
__global__ __launch_bounds__(256) void k_transpose(const float* __restrict__ vis,
                                                   __hip_bfloat16* __restrict__ visT2) {
  __shared__ float tile[8192];            // [c(128)][x(64)]
  const int by = blockIdx.x;              // b*64 + y
  const int b = by >> 6, y = by & 63;
  const int t = threadIdx.x;
  const float* src = vis + (size_t)b * 524288 + (size_t)(t >> 6) * 4096 + y * 64 + (t & 63);
  #pragma unroll
  for (int i = 0; i < 32; ++i)            // c = i*4 + (t>>6), x = t&63
    tile[(i * 4 + (t >> 6)) * 64 + (t & 63)] = src[(size_t)i * 4 * 4096];
  __syncthreads();
  bf16x8* dst = (bf16x8*)(visT2 + ((size_t)by << 13));   // by*16*512 elems
  #pragma unroll
  for (int k = 0; k < 4; ++k) {
    const int j = k * 256 + t;            // chunk: g = j>>6, x = j&63
    const int g = j >> 6, x = j & 63;
    union { bf16x8 v; __hip_bfloat16 h[8]; } u;
    #pragma unroll
    for (int cc = 0; cc < 8; ++cc)
      u.h[cc] = __float2bfloat16(tile[(g * 8 + cc) * 64 + x]);
    dst[j] = u.v;
  }
}

// ---------------- fused conv3x3 + bias + leaky + 31x31 maxpool (implicit GEMM, bf16 MFMA) ----------------
// R5: m201-style counted-vmcnt pipeline. 36 K-phases of K=32 (16 MFMA each), triple-buffered
// 48 KB LDS, stage(f+2) issued during phase f, s_waitcnt vmcnt(4) (never 0 in steady state),
// raw s_barrier (no vmcnt(0)/lgkmcnt(0) drain), setprio(1) around the MFMA cluster.
// Readiness invariant: ds_reads of buf[f%3] are pinned below iteration f-1's "memory"-clobbered
// vmcnt asm, which is exactly the point where stage(f) completion is guaranteed.
__global__ __launch_bounds__(256, 3) void k_conv(const __hip_bfloat16* __restrict__ visT2,
                                                 const __hip_bfloat16* __restrict__ Bt2,
                                                 const float* __restrict__ conv_b,
                                                 float* __restrict__ pooled_v) {
  __shared__ bf16x8 lds_a[3][512];   // 3 x 8 KB : [buf][sub(4)][m(128)]
  __shared__ bf16x8 lds_b[3][512];   // 3 x 8 KB : [buf][sub(4)][n(128)]
  const int bx = blockIdx.x;
  const int b = bx / 31;
  const int y0 = (bx - b * 31) * 2;
  const int tid = threadIdx.x;
  const int wave = tid >> 6, lane = tid & 63;
  const int quad = lane >> 4, l15 = lane & 15;

  f32x4 acc[8][2];
  #pragma unroll
  for (int i = 0; i < 8; ++i) {
    acc[i][0] = f32x4{0.f, 0.f, 0.f, 0.f};
    acc[i][1] = f32x4{0.f, 0.f, 0.f, 0.f};
  }

  const __hip_bfloat16* vb = visT2 + ((size_t)b << 19);   // b*64*16*512
  const int lane8 = lane << 3;

  // phase f2 = tap*4 + hk*2 + kh : stage A rows (y0+ky, y0+1+ky) subs hk*8+kh*4+{0..3}
  // and B rows (tap*2+hk)*8+kh*4+{0..3}; wave w stages sub w (4 gl_lds per wave).
  auto stage2 = [&](int f2, int bs) {
    const int tap = f2 >> 2, hk = (f2 >> 1) & 1, kh = f2 & 1;
    const int ky = tap / 3, kx = tap - ky * 3;
    const int sub = (hk << 3) + (kh << 2) + wave;
    const __hip_bfloat16* a0p = vb + ((size_t)(((y0 + ky) << 4) + sub) << 9) + (kx << 3) + lane8;
    const __hip_bfloat16* a1p = vb + ((size_t)(((y0 + 1 + ky) << 4) + sub) << 9) + (kx << 3) + lane8;
    bf16x8* ab = &lds_a[bs][wave << 7];
    gl_lds16(a0p, ab);          // m 0..63   (row0)
    gl_lds16(a1p, ab + 64);     // m 64..127 (row1)
    const __hip_bfloat16* bp = Bt2 + ((size_t)((((tap << 1) + hk) << 3) + (kh << 2) + wave) << 10) + lane8;
    bf16x8* bb = &lds_b[bs][wave << 7];
    gl_lds16(bp, bb);           // n 0..63
    gl_lds16(bp + 512, bb + 64);// n 64..127
  };

  // prologue: phases 0,1 staged; wait for phase 0 (leave phase 1's 4 loads in flight)
  stage2(0, 0);
  stage2(1, 1);
  asm volatile("s_waitcnt vmcnt(4)" ::: "memory");
  __builtin_amdgcn_s_barrier();

  for (int f = 0; f < 36; ++f) {
    const int bc = f % 3;
    const bf16x8* la = lds_a[bc];
    const bf16x8* lb = lds_b[bc];
    const bf16x8 b0 = lb[(quad << 7) + (wave << 5) + l15];
    const bf16x8 b1 = lb[(quad << 7) + (wave << 5) + 16 + l15];
    bf16x8 af[8];
    #pragma unroll
    for (int mt = 0; mt < 8; ++mt) af[mt] = la[(quad << 7) + (mt << 4) + l15];
    if (f < 34) {
      stage2(f + 2, (f + 2) % 3);
      asm volatile("s_waitcnt vmcnt(4)" ::: "memory");   // stage(f+1) done; stage(f+2) in flight
    } else if (f == 34) {
      asm volatile("s_waitcnt vmcnt(0)" ::: "memory");   // tail: drain stage(35)
    }
    __builtin_amdgcn_s_barrier();
    __builtin_amdgcn_s_setprio(1);
    #pragma unroll
    for (int mt = 0; mt < 8; ++mt) {
      acc[mt][0] = __builtin_amdgcn_mfma_f32_16x16x32_bf16(af[mt], b0, acc[mt][0], 0, 0, 0);
      acc[mt][1] = __builtin_amdgcn_mfma_f32_16x16x32_bf16(af[mt], b1, acc[mt][1], 0, 0, 0);
    }
    __builtin_amdgcn_s_setprio(0);
    __builtin_amdgcn_s_barrier();
  }

  // epilogue: bias + leaky + pool-max. C layout: n = nbase + l15, m = mt*16 + quad*4 + r.
  const float cb0 = conv_b[(wave << 5) + l15];
  const float cb1 = conv_b[(wave << 5) + 16 + l15];
  float pmax[2][2][2];
  #pragma unroll
  for (int i = 0; i < 8; ++i) (&pmax[0][0][0])[i] = -FLT_MAX;

  #pragma unroll
  for (int mt = 0; mt < 8; ++mt) {
    const int py = (y0 + (mt >> 2)) >= 31 ? 1 : 0;
    #pragma unroll
    for (int r = 0; r < 4; ++r) {
      const int x = ((mt & 3) << 4) + (quad << 2) + r;
      if (x < 62) {
        const int px = x >= 31 ? 1 : 0;
        float v0 = acc[mt][0][r] + cb0;  v0 = v0 >= 0.f ? v0 : 0.2f * v0;
        float v1 = acc[mt][1][r] + cb1;  v1 = v1 >= 0.f ? v1 : 0.2f * v1;
        pmax[0][py][px] = fmaxf(pmax[0][py][px], v0);
        pmax[1][py][px] = fmaxf(pmax[1][py][px], v1);
      }
    }
  }
  #pragma unroll
  for (int nt = 0; nt < 2; ++nt)
    #pragma unroll
    for (int py = 0; py < 2; ++py)
      #pragma unroll
      for (int px = 0; px < 2; ++px) {
        float v = pmax[nt][py][px];
        v = fmaxf(v, __shfl_xor(v, 16, 64));
        v = fmaxf(v, __shfl_xor(v, 32, 64));
        if (quad == 0) {
          const int n = (wave << 5) + (nt << 4) + l15;
          atomicMaxF(&pooled_v[(size_t)b * 512 + n * 4 + py * 2 + px], v);
        }
      }
}

// ---------------- vision FC (spectral-normed) ----------------
__global__ __launch_bounds__(256) void k_fcv(const float* __restrict__ pooled_v, const float* __restrict__ fcv_w,
                                             const float* __restrict__ fcv_b, const float* __restrict__ inv_sigma,
                                             float* __restrict__ out) {
  __shared__ float xr[512];
  const int b = blockIdx.x, tid = threadIdx.x;
  for (int f = tid; f < 512; f += 256) xr[f] = pooled_v[b * 512 + f];
  __syncthreads();
  float a = 0.f;
  const float* wr = fcv_w + (size_t)tid * 512;
  for (int f = 0; f < 512; ++f) a += xr[f] * wr[f];
  out[b * 256 + tid] = a * inv_sigma[1] + fcv_b[tid];
}

// ---------------- topo head: CSR build ----------------
__global__ void k_deg(const int* __restrict__ dst, int* __restrict__ cnt) {
  const int e = blockIdx.x * 256 + threadIdx.x;
  if (e < NEDGE) atomicAdd(&cnt[dst[e]], 1);
}

// exclusive prefix sum of cnt -> offset (single block, 256 threads x 79 nodes each)
__global__ __launch_bounds__(256) void k_scan(const int* __restrict__ cnt, int* __restrict__ offset) {
  __shared__ int red[256];
  const int tid = threadIdx.x;
  const int n0 = tid * 79;
  const int n1 = (n0 + 79 < NNODE) ? n0 + 79 : NNODE;
  int s = 0;
  for (int n = n0; n < n1; ++n) s += cnt[n];
  red[tid] = s; __syncthreads();
  for (int d = 1; d < 256; d <<= 1) {
    int v = (tid >= d) ? red[tid - d] : 0;
    __syncthreads();
    red[tid] += v;
    __syncthreads();
  }
  int run = (tid == 0) ? 0 : red[tid - 1];
  for (int n = n0; n < n1; ++n) { offset[n] = run; run += cnt[n]; }
}

__global__ void k_bucket(const int* __restrict__ src, const int* __restrict__ dst,
                         const int* __restrict__ offset, int* __restrict__ fill,
                         int* __restrict__ sorted_src) {
  const int e = blockIdx.x * 256 + threadIdx.x;
  if (e >= NEDGE) return;
  const int t = dst[e];
  const int pos = atomicAdd(&fill[t], 1);
  sorted_src[offset[t] + pos] = src[e];
}

__global__ void k_dis(const int* __restrict__ cnt, float* __restrict__ dis) {
  const int n = blockIdx.x * 256 + threadIdx.x;
  if (n < NNODE) dis[n] = rsqrtf((float)(cnt[n] + 1));
}

__global__ __launch_bounds__(256) void k_xw(const float* __restrict__ topo, const float* __restrict__ gcn_w,
                                            float* __restrict__ xw) {
  __shared__ float w[128 * 128];
  const int tid = threadIdx.x;
  for (int i = tid; i < 16384; i += 256) w[i] = gcn_w[i];
  __syncthreads();
  const int n0 = blockIdx.x * 64;
  const int j = tid & 127, half = tid >> 7;
  for (int nn = half; nn < 64; nn += 2) {
    const int n = n0 + nn;
    if (n >= NNODE) break;
    const float* tr = topo + (size_t)n * 128;
    float a = 0.f;
    for (int d = 0; d < 128; ++d) a += tr[d] * w[d * 128 + j];
    xw[(size_t)n * 128 + j] = a;
  }
}

// ---------------- GCN gather (CSR, no float atomics): h = leaky(b + dn*(dn*xw[n] + sum dis[s]*xw[s])) ----------------
__global__ __launch_bounds__(128) void k_gather(const int* __restrict__ sorted_src,
                                                const int* __restrict__ offset, const int* __restrict__ cnt,
                                                const float* __restrict__ dis, const float* __restrict__ xw,
                                                const float* __restrict__ gcn_b, float* __restrict__ h) {
  const int n = blockIdx.x;
  const int d = threadIdx.x;
  const int e0 = offset[n], ne = cnt[n];
  const float dn = dis[n];
  float acc = dn * xw[(size_t)n * 128 + d];   // self-loop (one dn factored outside)
  int e = 0;
  for (; e + 4 <= ne; e += 4) {
    const int s0 = sorted_src[e0 + e + 0];
    const int s1 = sorted_src[e0 + e + 1];
    const int s2 = sorted_src[e0 + e + 2];
    const int s3 = sorted_src[e0 + e + 3];
    const float x0 = xw[(size_t)s0 * 128 + d];
    const float x1 = xw[(size_t)s1 * 128 + d];
    const float x2 = xw[(size_t)s2 * 128 + d];
    const float x3 = xw[(size_t)s3 * 128 + d];
    acc += dis[s0] * x0 + dis[s1] * x1 + dis[s2] * x2 + dis[s3] * x3;
  }
  for (; e < ne; ++e) {
    const int s = sorted_src[e0 + e];
    acc += dis[s] * xw[(size_t)s * 128 + d];
  }
  float v = gcn_b[d] + dn * acc;
  v = v >= 0.f ? v : 0.2f * v;
  h[(size_t)n * 128 + d] = v;
}

__global__ void k_pool_t(const float* __restrict__ h, const int* __restrict__ batch,
                         float* __restrict__ pooled_t) {
  const int d = threadIdx.x;           // 128
  const int n0 = blockIdx.x * 32;
  float run = -FLT_MAX;
  int cur = batch[n0];
  for (int i = 0; i < 32; ++i) {
    const int n = n0 + i;
    const int g = batch[n];
    if (g != cur) {
      atomicMaxF(&pooled_t[cur * 128 + d], run);
      run = -FLT_MAX; cur = g;
    }
    run = fmaxf(run, h[(size_t)n * 128 + d]);
  }
  atomicMaxF(&pooled_t[cur * 128 + d], run);
}

__global__ __launch_bounds__(256) void k_fct(const float* __restrict__ pooled_t, const float* __restrict__ fct_w,
                                             const float* __restrict__ fct_b, const float* __restrict__ inv_sigma,
                                             float* __restrict__ out) {
  __shared__ float xr[128];
  const int b = blockIdx.x, tid = threadIdx.x;
  if (tid < 128) xr[tid] = pooled_t[b * 128 + tid];
  __syncthreads();
  float a = 0.f;
  const float* wr = fct_w + (size_t)tid * 128;
  for (int f = 0; f < 128; ++f) a += xr[f] * wr[f];
  out[NB * 256 + b * 256 + tid] = a * inv_sigma[2] + fct_b[tid];
}

extern "C" void kernel_launch(void* const* d_in, const int* in_sizes, int n_in,
                              void* d_out, int out_size, void* d_ws, size_t ws_size,
                              hipStream_t stream) {
  const float* vis    = (const float*)d_in[0];
  const float* topo   = (const float*)d_in[1];
  const int*   eidx   = (const int*)d_in[2];
  const int*   batch  = (const int*)d_in[3];
  const float* conv_w = (const float*)d_in[4];
  const float* conv_b = (const float*)d_in[5];
  const float* conv_u = (const float*)d_in[6];
  const float* fcv_w  = (const float*)d_in[7];
  const float* fcv_b  = (const float*)d_in[8];
  const float* fcv_u  = (const float*)d_in[9];
  const float* gcn_w  = (const float*)d_in[10];
  const float* gcn_b  = (const float*)d_in[11];
  const float* fct_w  = (const float*)d_in[12];
  const float* fct_b  = (const float*)d_in[13];
  const float* fct_u  = (const float*)d_in[14];
  float* out = (float*)d_out;

  char* p = (char*)d_ws;
  float* inv_sigma  = (float*)p; p += 256;
  float* sn_scratch = (float*)p; p += 1796 * 4 + 240;           // v0,v1,v2,ss (pad to 16B)
  float* pooled_v   = (float*)p; p += (size_t)NB * 512 * 4;     // 131072
  float* pooled_t   = (float*)p; p += (size_t)NB * 128 * 4;     // 32768
  int*   cnt        = (int*)p;   p += (size_t)NNODE * 4;
  int*   offset     = (int*)p;   p += (size_t)NNODE * 4;
  int*   fill       = (int*)p;   p += (size_t)NNODE * 4;
  float* dis        = (float*)p; p += (size_t)NNODE * 4;
  int*   sorted_src = (int*)p;   p += (size_t)NEDGE * 4;
  float* xw         = (float*)p; p += (size_t)NNODE * 128 * 4;
  float* h          = (float*)p; p += (size_t)NNODE * 128 * 4;
  __hip_bfloat16* Bt2 = (__hip_bfloat16*)p; p += (size_t)147456 * 2;
  p = (char*)(((uintptr_t)p + 255) & ~(uintptr_t)255);
  __hip_bfloat16* visT2 = (__hip_bfloat16*)p;                   // 64 MB + tail pad (OOB-read slack)

  // init + spectral norm (parallel 3-stage)
  hipLaunchKernelGGL(k_init,      dim3(128),   dim3(256), 0, stream, pooled_v, pooled_t, cnt, fill, sn_scratch);
  hipLaunchKernelGGL(k_sn_v,      dim3(20),    dim3(256), 0, stream, conv_w, conv_u, fcv_w, fcv_u, fct_w, fct_u, sn_scratch);
  hipLaunchKernelGGL(k_sn_w,      dim3(160),   dim3(256), 0, stream, conv_w, fcv_w, fct_w, sn_scratch);
  hipLaunchKernelGGL(k_sn_fin,    dim3(1),     dim3(256), 0, stream, sn_scratch, inv_sigma);
  // vision head
  hipLaunchKernelGGL(k_pack,      dim3(576),   dim3(256), 0, stream, conv_w, inv_sigma, Bt2);
  hipLaunchKernelGGL(k_transpose, dim3(4096),  dim3(256), 0, stream, vis, visT2);
  hipLaunchKernelGGL(k_conv,      dim3(64*31), dim3(256), 0, stream, visT2, Bt2, conv_b, pooled_v);
  hipLaunchKernelGGL(k_fcv,       dim3(64),    dim3(256), 0, stream, pooled_v, fcv_w, fcv_b, inv_sigma, out);
  // topo head: CSR build + gather, separate pool (R4 fusion was a ~20us regression)
  hipLaunchKernelGGL(k_deg,       dim3(2500),  dim3(256), 0, stream, eidx + NEDGE, cnt);
  hipLaunchKernelGGL(k_scan,      dim3(1),     dim3(256), 0, stream, cnt, offset);
  hipLaunchKernelGGL(k_bucket,    dim3(2500),  dim3(256), 0, stream, eidx, eidx + NEDGE, offset, fill, sorted_src);
  hipLaunchKernelGGL(k_dis,       dim3(79),    dim3(256), 0, stream, cnt, dis);
  hipLaunchKernelGGL(k_xw,        dim3(313),   dim3(256), 0, stream, topo, gcn_w, xw);
  hipLaunchKernelGGL(k_gather,    dim3(NNODE), dim3(128), 0, stream, sorted_src, offset, cnt, dis, xw, gcn_b, h);
  hipLaunchKernelGGL(k_pool_t,    dim3(625),   dim3(128), 0, stream, h, batch, pooled_t);
  hipLaunchKernelGGL(k_fct,       dim3(64),    dim3(256), 0, stream, pooled_t, fct_w, fct_b, inv_sigma, out);
}

// Round 3
// 588.187 us; speedup vs baseline: 1.1007x; 1.1007x over previous
//
#include <hip/hip_runtime.h>
#include <hip/hip_bf16.h>
#include <float.h>
#include <stdint.h>

// Problem constants
#define NB   64      // batch / num graphs
#define CD   128     // channels / dims
#define OUTD 256
#define NNODE 20000
#define NEDGE 640000

typedef __bf16 bf16x8 __attribute__((ext_vector_type(8)));
typedef float  f32x4  __attribute__((ext_vector_type(4)));

__device__ inline void gl_lds16(const void* g, void* l) {
  __builtin_amdgcn_global_load_lds(
      (const __attribute__((address_space(1))) void*)g,
      (__attribute__((address_space(3))) void*)l, 16, 0, 0);
}

// float atomic max via signed/unsigned int monotonic trick (works for mixed signs)
__device__ inline void atomicMaxF(float* addr, float val) {
  if (val >= 0.f) atomicMax((int*)addr, __float_as_int(val));
  else            atomicMin((unsigned int*)addr, __float_as_uint(val));
}

// ---------------- init: pooled buffers (-FLT_MAX), CSR counters (=0), SN scratch (=0) ----------------
// sn_scratch layout: [0..1151]=v0, [1152..1663]=v1, [1664..1791]=v2, [1792..1795]=ss
__global__ void k_init(float* __restrict__ pooled_v, float* __restrict__ pooled_t,
                       int* __restrict__ cnt, int* __restrict__ fill,
                       float* __restrict__ sn_scratch, int* __restrict__ ntotal) {
  const int i = blockIdx.x * 256 + threadIdx.x;   // grid covers 32768
  if (i < NB * CD * 4) pooled_v[i] = -FLT_MAX;
  if (i < NB * CD)     pooled_t[i] = -FLT_MAX;
  if (i < NNODE)       { cnt[i] = 0; fill[i] = 0; }
  if (i < 1796)        sn_scratch[i] = 0.0f;
  if (i == 0)          *ntotal = 0;
}

// ---------------- SN stage 1: v = W^T u, 32-row chunks, coalesced, atomicAdd per column ----------------
__global__ __launch_bounds__(256) void k_sn_v(const float* __restrict__ conv_w, const float* __restrict__ conv_u,
                                              const float* __restrict__ fcv_w,  const float* __restrict__ fcv_u,
                                              const float* __restrict__ fct_w,  const float* __restrict__ fct_u,
                                              float* __restrict__ sn) {
  const int bb = blockIdx.x;       // 0..19
  const float* W; const float* u; float* v; int C; int r0;
  if (bb < 4)       { W = conv_w; u = conv_u; v = sn;        C = 1152; r0 = bb * 32; }
  else if (bb < 12) { W = fcv_w;  u = fcv_u;  v = sn + 1152; C = 512;  r0 = (bb - 4) * 32; }
  else              { W = fct_w;  u = fct_u;  v = sn + 1664; C = 128;  r0 = (bb - 12) * 32; }
  const int tid = threadIdx.x;
  float acc[5] = {0.f, 0.f, 0.f, 0.f, 0.f};
  for (int i = r0; i < r0 + 32; ++i) {
    const float ui = u[i];
    const float* row = W + (size_t)i * C;
    #pragma unroll
    for (int t = 0; t < 5; ++t) {
      const int j = tid + t * 256;
      if (j < C) acc[t] += ui * row[j];
    }
  }
  #pragma unroll
  for (int t = 0; t < 5; ++t) {
    const int j = tid + t * 256;
    if (j < C) atomicAdd(&v[j], acc[t]);
  }
}

// ---------------- SN stage 2: ss[m] = ||W v||^2, one wave per row ----------------
__global__ __launch_bounds__(256) void k_sn_w(const float* __restrict__ conv_w,
                                              const float* __restrict__ fcv_w,
                                              const float* __restrict__ fct_w,
                                              float* __restrict__ sn) {
  const int gw = blockIdx.x * 4 + (threadIdx.x >> 6);   // global wave id, 0..639
  const int lane = threadIdx.x & 63;
  const float* W; const float* v; int C, m, row;
  if (gw < 128)      { W = conv_w; v = sn;        C = 1152; m = 0; row = gw; }
  else if (gw < 384) { W = fcv_w;  v = sn + 1152; C = 512;  m = 1; row = gw - 128; }
  else               { W = fct_w;  v = sn + 1664; C = 128;  m = 2; row = gw - 384; }
  const float* wr = W + (size_t)row * C;
  float y = 0.f;
  for (int c = lane; c < C; c += 64) y += wr[c] * v[c];
  #pragma unroll
  for (int s = 32; s > 0; s >>= 1) y += __shfl_xor(y, s, 64);
  if (lane == 0) atomicAdd(&sn[1792 + m], y * y);
}

// ---------------- SN stage 3: inv_sigma[m] = (||v||+eps)/||Wv|| ----------------
__global__ __launch_bounds__(256) void k_sn_fin(const float* __restrict__ sn, float* __restrict__ inv_sigma) {
  __shared__ float red[256];
  const int tid = threadIdx.x;
  const int off[4] = {0, 1152, 1664, 1792};
  for (int m = 0; m < 3; ++m) {
    const int C = off[m + 1] - off[m];
    float ss = 0.f;
    for (int j = tid; j < C; j += 256) { const float a = sn[off[m] + j]; ss += a * a; }
    red[tid] = ss; __syncthreads();
    for (int s = 128; s > 0; s >>= 1) { if (tid < s) red[tid] += red[tid + s]; __syncthreads(); }
    if (tid == 0) inv_sigma[m] = (sqrtf(red[0]) + 1e-12f) / sqrtf(sn[1792 + m]);
    __syncthreads();
  }
}

// ---------------- pack conv weights into staging-coalesced frag order ----------------
// Bt2[tap(9)][halfk(2)][sub(8)][n(128)][c8(8)] = conv_w[n][ci=hk*64+s*8+j][tap] / sigma
__global__ void k_pack(const float* __restrict__ conv_w, const float* __restrict__ inv_sigma,
                       __hip_bfloat16* __restrict__ Bt2) {
  const int t = blockIdx.x * 256 + threadIdx.x;
  if (t >= 147456) return;
  const int j = t & 7, n = (t >> 3) & 127, s = (t >> 10) & 7, hk = (t >> 13) & 1, tap = t >> 14;
  const int ci = hk * 64 + s * 8 + j;
  Bt2[t] = __float2bfloat16(conv_w[n * 1152 + ci * 9 + tap] * inv_sigma[0]);
}

// ---------------- NCHW f32 -> tiled bf16: visT2[b][y][g=c/8][x(64)][c8(8)] ----------------
__global__ __launch_bounds__(256) void k_transpose(const float* __restrict__ vis,
                                                   __hip_bfloat16* __restrict__ visT2) {
  __shared__ float tile[8192];            // [c(128)][x(64)]
  const int by = blockIdx.x;              // b*64 + y
  const int b = by >> 6, y = by & 63;
  const int t = threadIdx.x;
  const float* src = vis + (size_t)b * 524288 + (size_t)(t >> 6) * 4096 + y * 64 + (t & 63);
  #pragma unroll
  for (int i = 0; i < 32; ++i)            // c = i*4 + (t>>6), x = t&63
    tile[(i * 4 + (t >> 6)) * 64 + (t & 63)] = src[(size_t)i * 4 * 4096];
  __syncthreads();
  bf16x8* dst = (bf16x8*)(visT2 + ((size_t)by << 13));   // by*16*512 elems
  #pragma unroll
  for (int k = 0; k < 4; ++k) {
    const int j = k * 256 + t;            // chunk: g = j>>6, x = j&63
    const int g = j >> 6, x = j & 63;
    union { bf16x8 v; __hip_bfloat16 h[8]; } u;
    #pragma unroll
    for (int cc = 0; cc < 8; ++cc)
      u.h[cc] = __float2bfloat16(tile[(g * 8 + cc) * 64 + x]);
    dst[j] = u.v;
  }
}

// ---------------- fused conv3x3 + bias + leaky + 31x31 maxpool (implicit GEMM, bf16 MFMA) ----------------
// R4 structure (proven 94us). R5's counted-vmcnt 3-buffer variant regressed: +12% VALUBusy from
// runtime buffer indexing, -25% occupancy from 48KB LDS, 2x barrier count. Reverted.
__global__ __launch_bounds__(256, 4) void k_conv(const __hip_bfloat16* __restrict__ visT2,
                                                 const __hip_bfloat16* __restrict__ Bt2,
                                                 const float* __restrict__ conv_b,
                                                 float* __restrict__ pooled_v) {
  __shared__ bf16x8 lds_a[1024];   // 16 KB  [sub(8)][m(128)]
  __shared__ bf16x8 lds_b[1024];   // 16 KB  [sub(8)][n(128)]
  const int bx = blockIdx.x;
  const int b = bx / 31;
  const int y0 = (bx - b * 31) * 2;
  const int tid = threadIdx.x;
  const int wave = tid >> 6, lane = tid & 63;
  const int quad = lane >> 4, l15 = lane & 15;

  f32x4 acc[8][2];
  #pragma unroll
  for (int i = 0; i < 8; ++i) {
    acc[i][0] = f32x4{0.f, 0.f, 0.f, 0.f};
    acc[i][1] = f32x4{0.f, 0.f, 0.f, 0.f};
  }

  const __hip_bfloat16* vb = visT2 + ((size_t)b << 19);   // b*64*16*512
  const int s0 = wave << 1;                 // this wave stages subchunks s0, s0+1
  bf16x8* ldsA0 = &lds_a[s0 << 7];
  bf16x8* ldsB0 = &lds_b[s0 << 7];
  const int lane8 = lane << 3;

  for (int ky = 0; ky < 3; ++ky) {
    for (int kx = 0; kx < 3; ++kx) {
      const int tap = ky * 3 + kx;
      #pragma unroll
      for (int hk = 0; hk < 2; ++hk) {
        // A: visT2 row-group (y, g=hk*8+s); kx shift = +kx*8 elems; lanes contiguous.
        const __hip_bfloat16* a0p = vb + ((size_t)(((y0 + ky) << 4) + (hk << 3) + s0) << 9) + (kx << 3) + lane8;
        const __hip_bfloat16* a1p = vb + ((size_t)(((y0 + 1 + ky) << 4) + (hk << 3) + s0) << 9) + (kx << 3) + lane8;
        const __hip_bfloat16* bp  = Bt2 + (((size_t)(((tap << 1) + hk) << 3) + s0) << 10) + lane8;
        gl_lds16(a0p,        ldsA0);         // sub s0, m 0..63   (row0)
        gl_lds16(a1p,        ldsA0 + 64);    // sub s0, m 64..127 (row1)
        gl_lds16(a0p + 512,  ldsA0 + 128);   // sub s0+1, row0
        gl_lds16(a1p + 512,  ldsA0 + 192);   // sub s0+1, row1
        gl_lds16(bp,         ldsB0);         // sub s0, n 0..63
        gl_lds16(bp + 512,   ldsB0 + 64);    // sub s0, n 64..127
        gl_lds16(bp + 1024,  ldsB0 + 128);   // sub s0+1, n 0..63
        gl_lds16(bp + 1536,  ldsB0 + 192);   // sub s0+1, n 64..127
        __syncthreads();
        const bf16x8 b00 = lds_b[(quad << 7) + (wave << 5) + l15];
        const bf16x8 b01 = lds_b[(quad << 7) + (wave << 5) + 16 + l15];
        const bf16x8 b10 = lds_b[((4 + quad) << 7) + (wave << 5) + l15];
        const bf16x8 b11 = lds_b[((4 + quad) << 7) + (wave << 5) + 16 + l15];
        #pragma unroll
        for (int mt = 0; mt < 8; ++mt) {
          const bf16x8 a0 = lds_a[(quad << 7) + (mt << 4) + l15];
          const bf16x8 a1 = lds_a[((4 + quad) << 7) + (mt << 4) + l15];
          acc[mt][0] = __builtin_amdgcn_mfma_f32_16x16x32_bf16(a0, b00, acc[mt][0], 0, 0, 0);
          acc[mt][1] = __builtin_amdgcn_mfma_f32_16x16x32_bf16(a0, b01, acc[mt][1], 0, 0, 0);
          acc[mt][0] = __builtin_amdgcn_mfma_f32_16x16x32_bf16(a1, b10, acc[mt][0], 0, 0, 0);
          acc[mt][1] = __builtin_amdgcn_mfma_f32_16x16x32_bf16(a1, b11, acc[mt][1], 0, 0, 0);
        }
        __syncthreads();
      }
    }
  }

  // epilogue: bias + leaky + pool-max. C layout: n = nbase + l15, m = mt*16 + quad*4 + r.
  const float cb0 = conv_b[(wave << 5) + l15];
  const float cb1 = conv_b[(wave << 5) + 16 + l15];
  float pmax[2][2][2];
  #pragma unroll
  for (int i = 0; i < 8; ++i) (&pmax[0][0][0])[i] = -FLT_MAX;

  #pragma unroll
  for (int mt = 0; mt < 8; ++mt) {
    const int py = (y0 + (mt >> 2)) >= 31 ? 1 : 0;
    #pragma unroll
    for (int r = 0; r < 4; ++r) {
      const int x = ((mt & 3) << 4) + (quad << 2) + r;
      if (x < 62) {
        const int px = x >= 31 ? 1 : 0;
        float v0 = acc[mt][0][r] + cb0;  v0 = v0 >= 0.f ? v0 : 0.2f * v0;
        float v1 = acc[mt][1][r] + cb1;  v1 = v1 >= 0.f ? v1 : 0.2f * v1;
        pmax[0][py][px] = fmaxf(pmax[0][py][px], v0);
        pmax[1][py][px] = fmaxf(pmax[1][py][px], v1);
      }
    }
  }
  #pragma unroll
  for (int nt = 0; nt < 2; ++nt)
    #pragma unroll
    for (int py = 0; py < 2; ++py)
      #pragma unroll
      for (int px = 0; px < 2; ++px) {
        float v = pmax[nt][py][px];
        v = fmaxf(v, __shfl_xor(v, 16, 64));
        v = fmaxf(v, __shfl_xor(v, 32, 64));
        if (quad == 0) {
          const int n = (wave << 5) + (nt << 4) + l15;
          atomicMaxF(&pooled_v[(size_t)b * 512 + n * 4 + py * 2 + px], v);
        }
      }
}

// ---------------- vision FC (spectral-normed), float4 dot ----------------
__global__ __launch_bounds__(256) void k_fcv(const float* __restrict__ pooled_v, const float* __restrict__ fcv_w,
                                             const float* __restrict__ fcv_b, const float* __restrict__ inv_sigma,
                                             float* __restrict__ out) {
  __shared__ f32x4 xr[128];
  const int b = blockIdx.x, tid = threadIdx.x;
  if (tid < 128) xr[tid] = ((const f32x4*)pooled_v)[b * 128 + tid];
  __syncthreads();
  const f32x4* wr = (const f32x4*)(fcv_w + (size_t)tid * 512);
  f32x4 a4 = {0.f, 0.f, 0.f, 0.f};
  for (int f = 0; f < 128; ++f) {
    const f32x4 x = xr[f];
    const f32x4 w = wr[f];
    #pragma unroll
    for (int k = 0; k < 4; ++k) a4[k] += x[k] * w[k];
  }
  const float a = a4[0] + a4[1] + a4[2] + a4[3];
  out[b * 256 + tid] = a * inv_sigma[1] + fcv_b[tid];
}

// ---------------- topo head: CSR build ----------------
__global__ void k_deg(const int* __restrict__ dst, int* __restrict__ cnt) {
  const int e = blockIdx.x * 256 + threadIdx.x;
  if (e < NEDGE) atomicAdd(&cnt[dst[e]], 1);
}

// parallel exclusive "scan": per-256-chunk local scan + atomic chunk base.
// Bucket ranges only need to be disjoint+sized, not monotone, so atomic ordering is fine.
__global__ __launch_bounds__(256) void k_scan(const int* __restrict__ cnt, int* __restrict__ offset,
                                              int* __restrict__ total) {
  __shared__ int red[256];
  __shared__ int sbase;
  const int tid = threadIdx.x;
  const int n = blockIdx.x * 256 + tid;
  const int v = (n < NNODE) ? cnt[n] : 0;
  red[tid] = v; __syncthreads();
  for (int d = 1; d < 256; d <<= 1) {
    const int t = (tid >= d) ? red[tid - d] : 0;
    __syncthreads();
    red[tid] += t;
    __syncthreads();
  }
  if (tid == 255) sbase = atomicAdd(total, red[255]);
  __syncthreads();
  if (n < NNODE) offset[n] = sbase + red[tid] - v;
}

__global__ void k_bucket(const int* __restrict__ src, const int* __restrict__ dst,
                         const int* __restrict__ offset, int* __restrict__ fill,
                         int* __restrict__ sorted_src) {
  const int e = blockIdx.x * 256 + threadIdx.x;
  if (e >= NEDGE) return;
  const int t = dst[e];
  const int pos = atomicAdd(&fill[t], 1);
  sorted_src[offset[t] + pos] = src[e];
}

__global__ void k_dis(const int* __restrict__ cnt, float* __restrict__ dis) {
  const int n = blockIdx.x * 256 + threadIdx.x;
  if (n < NNODE) dis[n] = rsqrtf((float)(cnt[n] + 1));
}

// ---------------- xw = topo @ gcn_w, float4 both sides (LDS weights) ----------------
__global__ __launch_bounds__(256) void k_xw(const float* __restrict__ topo, const float* __restrict__ gcn_w,
                                            float* __restrict__ xw) {
  __shared__ f32x4 w4[4096];             // 64 KB: [d(128)][jq(32)]
  const int tid = threadIdx.x;
  const f32x4* gw4 = (const f32x4*)gcn_w;
  for (int i = tid; i < 4096; i += 256) w4[i] = gw4[i];
  __syncthreads();
  const int n0 = blockIdx.x * 64;
  const int jq = tid & 31, ns = tid >> 5;          // 8 nodes per pass
  for (int pass = 0; pass < 8; ++pass) {
    const int n = n0 + pass * 8 + ns;
    if (n >= NNODE) break;
    const f32x4* tr4 = (const f32x4*)(topo + (size_t)n * 128);
    f32x4 a = {0.f, 0.f, 0.f, 0.f};
    for (int d4 = 0; d4 < 32; ++d4) {
      const f32x4 t = tr4[d4];
      const int base = (d4 << 7) + jq;             // (d4*4)*32 + jq
      #pragma unroll
      for (int m = 0; m < 4; ++m) {
        const f32x4 w = w4[base + m * 32];
        #pragma unroll
        for (int k = 0; k < 4; ++k) a[k] += t[m] * w[k];
      }
    }
    ((f32x4*)xw)[(size_t)n * 32 + jq] = a;
  }
}

// ---------------- GCN gather: 8-way edge-parallel x float4, LDS tree-reduce ----------------
// h[n] = leaky(b + dn*(dn*xw[n] + sum_e dis[s_e]*xw[s_e]))
__global__ __launch_bounds__(256) void k_gather(const int* __restrict__ sorted_src,
                                                const int* __restrict__ offset, const int* __restrict__ cnt,
                                                const float* __restrict__ dis, const float* __restrict__ xw,
                                                const float* __restrict__ gcn_b, float* __restrict__ h) {
  __shared__ f32x4 red[256];
  const int n = blockIdx.x;
  const int tid = threadIdx.x;
  const int es = tid >> 5;          // edge slot 0..7
  const int d4 = tid & 31;          // float4 column
  const int e0 = offset[n], ne = cnt[n];
  const float dn = dis[n];
  const f32x4* xw4 = (const f32x4*)xw;
  f32x4 a = {0.f, 0.f, 0.f, 0.f};
  if (es == 0) {                    // self-loop (one dn factored outside)
    const f32x4 x = xw4[(size_t)n * 32 + d4];
    #pragma unroll
    for (int k = 0; k < 4; ++k) a[k] = dn * x[k];
  }
  for (int e = es; e < ne; e += 8) {
    const int s = sorted_src[e0 + e];
    const float w = dis[s];
    const f32x4 x = xw4[(size_t)s * 32 + d4];
    #pragma unroll
    for (int k = 0; k < 4; ++k) a[k] += w * x[k];
  }
  red[tid] = a;
  __syncthreads();
  if (tid < 128) {
    #pragma unroll
    for (int k = 0; k < 4; ++k) red[tid][k] += red[tid + 128][k];
  }
  __syncthreads();
  if (tid < 64) {
    #pragma unroll
    for (int k = 0; k < 4; ++k) red[tid][k] += red[tid + 64][k];
  }
  __syncthreads();
  if (tid < 32) {
    f32x4 r = red[tid];
    const f32x4 r2 = red[tid + 32];
    const f32x4 gb = ((const f32x4*)gcn_b)[tid];
    f32x4 v;
    #pragma unroll
    for (int k = 0; k < 4; ++k) {
      float t = gb[k] + dn * (r[k] + r2[k]);
      v[k] = t >= 0.f ? t : 0.2f * t;
    }
    ((f32x4*)h)[(size_t)n * 32 + tid] = v;
  }
}

__global__ void k_pool_t(const float* __restrict__ h, const int* __restrict__ batch,
                         float* __restrict__ pooled_t) {
  const int d = threadIdx.x;           // 128
  const int n0 = blockIdx.x * 32;
  float run = -FLT_MAX;
  int cur = batch[n0];
  for (int i = 0; i < 32; ++i) {
    const int n = n0 + i;
    const int g = batch[n];
    if (g != cur) {
      atomicMaxF(&pooled_t[cur * 128 + d], run);
      run = -FLT_MAX; cur = g;
    }
    run = fmaxf(run, h[(size_t)n * 128 + d]);
  }
  atomicMaxF(&pooled_t[cur * 128 + d], run);
}

__global__ __launch_bounds__(256) void k_fct(const float* __restrict__ pooled_t, const float* __restrict__ fct_w,
                                             const float* __restrict__ fct_b, const float* __restrict__ inv_sigma,
                                             float* __restrict__ out) {
  __shared__ f32x4 xr[32];
  const int b = blockIdx.x, tid = threadIdx.x;
  if (tid < 32) xr[tid] = ((const f32x4*)pooled_t)[b * 32 + tid];
  __syncthreads();
  const f32x4* wr = (const f32x4*)(fct_w + (size_t)tid * 128);
  f32x4 a4 = {0.f, 0.f, 0.f, 0.f};
  for (int f = 0; f < 32; ++f) {
    const f32x4 x = xr[f];
    const f32x4 w = wr[f];
    #pragma unroll
    for (int k = 0; k < 4; ++k) a4[k] += x[k] * w[k];
  }
  const float a = a4[0] + a4[1] + a4[2] + a4[3];
  out[NB * 256 + b * 256 + tid] = a * inv_sigma[2] + fct_b[tid];
}

extern "C" void kernel_launch(void* const* d_in, const int* in_sizes, int n_in,
                              void* d_out, int out_size, void* d_ws, size_t ws_size,
                              hipStream_t stream) {
  const float* vis    = (const float*)d_in[0];
  const float* topo   = (const float*)d_in[1];
  const int*   eidx   = (const int*)d_in[2];
  const int*   batch  = (const int*)d_in[3];
  const float* conv_w = (const float*)d_in[4];
  const float* conv_b = (const float*)d_in[5];
  const float* conv_u = (const float*)d_in[6];
  const float* fcv_w  = (const float*)d_in[7];
  const float* fcv_b  = (const float*)d_in[8];
  const float* fcv_u  = (const float*)d_in[9];
  const float* gcn_w  = (const float*)d_in[10];
  const float* gcn_b  = (const float*)d_in[11];
  const float* fct_w  = (const float*)d_in[12];
  const float* fct_b  = (const float*)d_in[13];
  const float* fct_u  = (const float*)d_in[14];
  float* out = (float*)d_out;

  char* p = (char*)d_ws;
  float* inv_sigma  = (float*)p; p += 256;
  float* sn_scratch = (float*)p; p += 1796 * 4 + 240;           // v0,v1,v2,ss (pad to 16B)
  float* pooled_v   = (float*)p; p += (size_t)NB * 512 * 4;     // 131072
  float* pooled_t   = (float*)p; p += (size_t)NB * 128 * 4;     // 32768
  int*   cnt        = (int*)p;   p += (size_t)NNODE * 4;
  int*   offset     = (int*)p;   p += (size_t)NNODE * 4;
  int*   fill       = (int*)p;   p += (size_t)NNODE * 4;
  float* dis        = (float*)p; p += (size_t)NNODE * 4;
  int*   ntotal     = (int*)p;   p += 256;
  int*   sorted_src = (int*)p;   p += (size_t)NEDGE * 4;
  float* xw         = (float*)p; p += (size_t)NNODE * 128 * 4;
  float* h          = (float*)p; p += (size_t)NNODE * 128 * 4;
  __hip_bfloat16* Bt2 = (__hip_bfloat16*)p; p += (size_t)147456 * 2;
  p = (char*)(((uintptr_t)p + 255) & ~(uintptr_t)255);
  __hip_bfloat16* visT2 = (__hip_bfloat16*)p;                   // 64 MB + tail pad (OOB-read slack)

  // init + spectral norm (parallel 3-stage)
  hipLaunchKernelGGL(k_init,      dim3(128),   dim3(256), 0, stream, pooled_v, pooled_t, cnt, fill, sn_scratch, ntotal);
  hipLaunchKernelGGL(k_sn_v,      dim3(20),    dim3(256), 0, stream, conv_w, conv_u, fcv_w, fcv_u, fct_w, fct_u, sn_scratch);
  hipLaunchKernelGGL(k_sn_w,      dim3(160),   dim3(256), 0, stream, conv_w, fcv_w, fct_w, sn_scratch);
  hipLaunchKernelGGL(k_sn_fin,    dim3(1),     dim3(256), 0, stream, sn_scratch, inv_sigma);
  // vision head
  hipLaunchKernelGGL(k_pack,      dim3(576),   dim3(256), 0, stream, conv_w, inv_sigma, Bt2);
  hipLaunchKernelGGL(k_transpose, dim3(4096),  dim3(256), 0, stream, vis, visT2);
  hipLaunchKernelGGL(k_conv,      dim3(64*31), dim3(256), 0, stream, visT2, Bt2, conv_b, pooled_v);
  hipLaunchKernelGGL(k_fcv,       dim3(64),    dim3(256), 0, stream, pooled_v, fcv_w, fcv_b, inv_sigma, out);
  // topo head: CSR build + gather, separate pool (R4 fusion was a ~20us regression)
  hipLaunchKernelGGL(k_deg,       dim3(2500),  dim3(256), 0, stream, eidx + NEDGE, cnt);
  hipLaunchKernelGGL(k_scan,      dim3(79),    dim3(256), 0, stream, cnt, offset, ntotal);
  hipLaunchKernelGGL(k_bucket,    dim3(2500),  dim3(256), 0, stream, eidx, eidx + NEDGE, offset, fill, sorted_src);
  hipLaunchKernelGGL(k_dis,       dim3(79),    dim3(256), 0, stream, cnt, dis);
  hipLaunchKernelGGL(k_xw,        dim3(313),   dim3(256), 0, stream, topo, gcn_w, xw);
  hipLaunchKernelGGL(k_gather,    dim3(NNODE), dim3(256), 0, stream, sorted_src, offset, cnt, dis, xw, gcn_b, h);
  hipLaunchKernelGGL(k_pool_t,    dim3(625),   dim3(128), 0, stream, h, batch, pooled_t);
  hipLaunchKernelGGL(k_fct,       dim3(64),    dim3(256), 0, stream, pooled_t, fct_w, fct_b, inv_sigma, out);
}

// Round 4
// 554.579 us; speedup vs baseline: 1.1674x; 1.0606x over previous
//
#include <hip/hip_runtime.h>
#include <hip/hip_bf16.h>
#include <float.h>
#include <stdint.h>

// Problem constants
#define NB   64      // batch / num graphs
#define CD   128     // channels / dims
#define OUTD 256
#define NNODE 20000
#define NEDGE 640000

typedef __bf16 bf16x8 __attribute__((ext_vector_type(8)));
typedef __bf16 bf16x4 __attribute__((ext_vector_type(4)));
typedef float  f32x4  __attribute__((ext_vector_type(4)));

__device__ inline void gl_lds16(const void* g, void* l) {
  __builtin_amdgcn_global_load_lds(
      (const __attribute__((address_space(1))) void*)g,
      (__attribute__((address_space(3))) void*)l, 16, 0, 0);
}

// float atomic max via signed/unsigned int monotonic trick (works for mixed signs)
__device__ inline void atomicMaxF(float* addr, float val) {
  if (val >= 0.f) atomicMax((int*)addr, __float_as_int(val));
  else            atomicMin((unsigned int*)addr, __float_as_uint(val));
}

// ---------------- init: pooled buffers (-FLT_MAX), CSR counters (=0), SN scratch (=0) ----------------
// sn_scratch layout: [0..1151]=v0, [1152..1663]=v1, [1664..1791]=v2, [1792..1795]=ss
__global__ void k_init(float* __restrict__ pooled_v, float* __restrict__ pooled_t,
                       int* __restrict__ cnt, int* __restrict__ fill,
                       float* __restrict__ sn_scratch, int* __restrict__ ntotal) {
  const int i = blockIdx.x * 256 + threadIdx.x;   // grid covers 32768
  if (i < NB * CD * 4) pooled_v[i] = -FLT_MAX;
  if (i < NB * CD)     pooled_t[i] = -FLT_MAX;
  if (i < NNODE)       { cnt[i] = 0; fill[i] = 0; }
  if (i < 1796)        sn_scratch[i] = 0.0f;
  if (i == 0)          *ntotal = 0;
}

// ---------------- SN stage 1: v = W^T u, 32-row chunks, coalesced, atomicAdd per column ----------------
__global__ __launch_bounds__(256) void k_sn_v(const float* __restrict__ conv_w, const float* __restrict__ conv_u,
                                              const float* __restrict__ fcv_w,  const float* __restrict__ fcv_u,
                                              const float* __restrict__ fct_w,  const float* __restrict__ fct_u,
                                              float* __restrict__ sn) {
  const int bb = blockIdx.x;       // 0..19
  const float* W; const float* u; float* v; int C; int r0;
  if (bb < 4)       { W = conv_w; u = conv_u; v = sn;        C = 1152; r0 = bb * 32; }
  else if (bb < 12) { W = fcv_w;  u = fcv_u;  v = sn + 1152; C = 512;  r0 = (bb - 4) * 32; }
  else              { W = fct_w;  u = fct_u;  v = sn + 1664; C = 128;  r0 = (bb - 12) * 32; }
  const int tid = threadIdx.x;
  float acc[5] = {0.f, 0.f, 0.f, 0.f, 0.f};
  for (int i = r0; i < r0 + 32; ++i) {
    const float ui = u[i];
    const float* row = W + (size_t)i * C;
    #pragma unroll
    for (int t = 0; t < 5; ++t) {
      const int j = tid + t * 256;
      if (j < C) acc[t] += ui * row[j];
    }
  }
  #pragma unroll
  for (int t = 0; t < 5; ++t) {
    const int j = tid + t * 256;
    if (j < C) atomicAdd(&v[j], acc[t]);
  }
}

// ---------------- SN stage 2: ss[m] = ||W v||^2, one wave per row ----------------
__global__ __launch_bounds__(256) void k_sn_w(const float* __restrict__ conv_w,
                                              const float* __restrict__ fcv_w,
                                              const float* __restrict__ fct_w,
                                              float* __restrict__ sn) {
  const int gw = blockIdx.x * 4 + (threadIdx.x >> 6);   // global wave id, 0..639
  const int lane = threadIdx.x & 63;
  const float* W; const float* v; int C, m, row;
  if (gw < 128)      { W = conv_w; v = sn;        C = 1152; m = 0; row = gw; }
  else if (gw < 384) { W = fcv_w;  v = sn + 1152; C = 512;  m = 1; row = gw - 128; }
  else               { W = fct_w;  v = sn + 1664; C = 128;  m = 2; row = gw - 384; }
  const float* wr = W + (size_t)row * C;
  float y = 0.f;
  for (int c = lane; c < C; c += 64) y += wr[c] * v[c];
  #pragma unroll
  for (int s = 32; s > 0; s >>= 1) y += __shfl_xor(y, s, 64);
  if (lane == 0) atomicAdd(&sn[1792 + m], y * y);
}

// ---------------- SN stage 3: inv_sigma[m] = (||v||+eps)/||Wv|| ----------------
__global__ __launch_bounds__(256) void k_sn_fin(const float* __restrict__ sn, float* __restrict__ inv_sigma) {
  __shared__ float red[256];
  const int tid = threadIdx.x;
  const int off[4] = {0, 1152, 1664, 1792};
  for (int m = 0; m < 3; ++m) {
    const int C = off[m + 1] - off[m];
    float ss = 0.f;
    for (int j = tid; j < C; j += 256) { const float a = sn[off[m] + j]; ss += a * a; }
    red[tid] = ss; __syncthreads();
    for (int s = 128; s > 0; s >>= 1) { if (tid < s) red[tid] += red[tid + s]; __syncthreads(); }
    if (tid == 0) inv_sigma[m] = (sqrtf(red[0]) + 1e-12f) / sqrtf(sn[1792 + m]);
    __syncthreads();
  }
}

// ---------------- pack conv weights into staging-coalesced frag order ----------------
// Bt2[tap(9)][halfk(2)][sub(8)][n(128)][c8(8)] = conv_w[n][ci=hk*64+s*8+j][tap] / sigma
__global__ void k_pack(const float* __restrict__ conv_w, const float* __restrict__ inv_sigma,
                       __hip_bfloat16* __restrict__ Bt2) {
  const int t = blockIdx.x * 256 + threadIdx.x;
  if (t >= 147456) return;
  const int j = t & 7, n = (t >> 3) & 127, s = (t >> 10) & 7, hk = (t >> 13) & 1, tap = t >> 14;
  const int ci = hk * 64 + s * 8 + j;
  Bt2[t] = __float2bfloat16(conv_w[n * 1152 + ci * 9 + tap] * inv_sigma[0]);
}

// ---------------- NCHW f32 -> tiled bf16: visT2[b][y][g=c/8][x(64)][c8(8)] ----------------
__global__ __launch_bounds__(256) void k_transpose(const float* __restrict__ vis,
                                                   __hip_bfloat16* __restrict__ visT2) {
  __shared__ float tile[8192];            // [c(128)][x(64)]
  const int by = blockIdx.x;              // b*64 + y
  const int b = by >> 6, y = by & 63;
  const int t = threadIdx.x;
  const float* src = vis + (size_t)b * 524288 + (size_t)(t >> 6) * 4096 + y * 64 + (t & 63);
  #pragma unroll
  for (int i = 0; i < 32; ++i)            // c = i*4 + (t>>6), x = t&63
    tile[(i * 4 + (t >> 6)) * 64 + (t & 63)] = src[(size_t)i * 4 * 4096];
  __syncthreads();
  bf16x8* dst = (bf16x8*)(visT2 + ((size_t)by << 13));   // by*16*512 elems
  #pragma unroll
  for (int k = 0; k < 4; ++k) {
    const int j = k * 256 + t;            // chunk: g = j>>6, x = j&63
    const int g = j >> 6, x = j & 63;
    union { bf16x8 v; __hip_bfloat16 h[8]; } u;
    #pragma unroll
    for (int cc = 0; cc < 8; ++cc)
      u.h[cc] = __float2bfloat16(tile[(g * 8 + cc) * 64 + x]);
    dst[j] = u.v;
  }
}

// ---------------- fused conv3x3 + bias + leaky + 31x31 maxpool (implicit GEMM, bf16 MFMA) ----------------
// R4 structure (proven 94us). R5's counted-vmcnt 3-buffer variant regressed: +12% VALUBusy from
// runtime buffer indexing, -25% occupancy from 48KB LDS, 2x barrier count. Reverted.
__global__ __launch_bounds__(256, 4) void k_conv(const __hip_bfloat16* __restrict__ visT2,
                                                 const __hip_bfloat16* __restrict__ Bt2,
                                                 const float* __restrict__ conv_b,
                                                 float* __restrict__ pooled_v) {
  __shared__ bf16x8 lds_a[1024];   // 16 KB  [sub(8)][m(128)]
  __shared__ bf16x8 lds_b[1024];   // 16 KB  [sub(8)][n(128)]
  const int bx = blockIdx.x;
  const int b = bx / 31;
  const int y0 = (bx - b * 31) * 2;
  const int tid = threadIdx.x;
  const int wave = tid >> 6, lane = tid & 63;
  const int quad = lane >> 4, l15 = lane & 15;

  f32x4 acc[8][2];
  #pragma unroll
  for (int i = 0; i < 8; ++i) {
    acc[i][0] = f32x4{0.f, 0.f, 0.f, 0.f};
    acc[i][1] = f32x4{0.f, 0.f, 0.f, 0.f};
  }

  const __hip_bfloat16* vb = visT2 + ((size_t)b << 19);   // b*64*16*512
  const int s0 = wave << 1;                 // this wave stages subchunks s0, s0+1
  bf16x8* ldsA0 = &lds_a[s0 << 7];
  bf16x8* ldsB0 = &lds_b[s0 << 7];
  const int lane8 = lane << 3;

  for (int ky = 0; ky < 3; ++ky) {
    for (int kx = 0; kx < 3; ++kx) {
      const int tap = ky * 3 + kx;
      #pragma unroll
      for (int hk = 0; hk < 2; ++hk) {
        // A: visT2 row-group (y, g=hk*8+s); kx shift = +kx*8 elems; lanes contiguous.
        const __hip_bfloat16* a0p = vb + ((size_t)(((y0 + ky) << 4) + (hk << 3) + s0) << 9) + (kx << 3) + lane8;
        const __hip_bfloat16* a1p = vb + ((size_t)(((y0 + 1 + ky) << 4) + (hk << 3) + s0) << 9) + (kx << 3) + lane8;
        const __hip_bfloat16* bp  = Bt2 + (((size_t)(((tap << 1) + hk) << 3) + s0) << 10) + lane8;
        gl_lds16(a0p,        ldsA0);         // sub s0, m 0..63   (row0)
        gl_lds16(a1p,        ldsA0 + 64);    // sub s0, m 64..127 (row1)
        gl_lds16(a0p + 512,  ldsA0 + 128);   // sub s0+1, row0
        gl_lds16(a1p + 512,  ldsA0 + 192);   // sub s0+1, row1
        gl_lds16(bp,         ldsB0);         // sub s0, n 0..63
        gl_lds16(bp + 512,   ldsB0 + 64);    // sub s0, n 64..127
        gl_lds16(bp + 1024,  ldsB0 + 128);   // sub s0+1, n 0..63
        gl_lds16(bp + 1536,  ldsB0 + 192);   // sub s0+1, n 64..127
        __syncthreads();
        const bf16x8 b00 = lds_b[(quad << 7) + (wave << 5) + l15];
        const bf16x8 b01 = lds_b[(quad << 7) + (wave << 5) + 16 + l15];
        const bf16x8 b10 = lds_b[((4 + quad) << 7) + (wave << 5) + l15];
        const bf16x8 b11 = lds_b[((4 + quad) << 7) + (wave << 5) + 16 + l15];
        #pragma unroll
        for (int mt = 0; mt < 8; ++mt) {
          const bf16x8 a0 = lds_a[(quad << 7) + (mt << 4) + l15];
          const bf16x8 a1 = lds_a[((4 + quad) << 7) + (mt << 4) + l15];
          acc[mt][0] = __builtin_amdgcn_mfma_f32_16x16x32_bf16(a0, b00, acc[mt][0], 0, 0, 0);
          acc[mt][1] = __builtin_amdgcn_mfma_f32_16x16x32_bf16(a0, b01, acc[mt][1], 0, 0, 0);
          acc[mt][0] = __builtin_amdgcn_mfma_f32_16x16x32_bf16(a1, b10, acc[mt][0], 0, 0, 0);
          acc[mt][1] = __builtin_amdgcn_mfma_f32_16x16x32_bf16(a1, b11, acc[mt][1], 0, 0, 0);
        }
        __syncthreads();
      }
    }
  }

  // epilogue: bias + leaky + pool-max. C layout: n = nbase + l15, m = mt*16 + quad*4 + r.
  const float cb0 = conv_b[(wave << 5) + l15];
  const float cb1 = conv_b[(wave << 5) + 16 + l15];
  float pmax[2][2][2];
  #pragma unroll
  for (int i = 0; i < 8; ++i) (&pmax[0][0][0])[i] = -FLT_MAX;

  #pragma unroll
  for (int mt = 0; mt < 8; ++mt) {
    const int py = (y0 + (mt >> 2)) >= 31 ? 1 : 0;
    #pragma unroll
    for (int r = 0; r < 4; ++r) {
      const int x = ((mt & 3) << 4) + (quad << 2) + r;
      if (x < 62) {
        const int px = x >= 31 ? 1 : 0;
        float v0 = acc[mt][0][r] + cb0;  v0 = v0 >= 0.f ? v0 : 0.2f * v0;
        float v1 = acc[mt][1][r] + cb1;  v1 = v1 >= 0.f ? v1 : 0.2f * v1;
        pmax[0][py][px] = fmaxf(pmax[0][py][px], v0);
        pmax[1][py][px] = fmaxf(pmax[1][py][px], v1);
      }
    }
  }
  #pragma unroll
  for (int nt = 0; nt < 2; ++nt)
    #pragma unroll
    for (int py = 0; py < 2; ++py)
      #pragma unroll
      for (int px = 0; px < 2; ++px) {
        float v = pmax[nt][py][px];
        v = fmaxf(v, __shfl_xor(v, 16, 64));
        v = fmaxf(v, __shfl_xor(v, 32, 64));
        if (quad == 0) {
          const int n = (wave << 5) + (nt << 4) + l15;
          atomicMaxF(&pooled_v[(size_t)b * 512 + n * 4 + py * 2 + px], v);
        }
      }
}

// ---------------- topo head: CSR build ----------------
__global__ void k_deg(const int* __restrict__ dst, int* __restrict__ cnt) {
  const int e = blockIdx.x * 256 + threadIdx.x;
  if (e < NEDGE) atomicAdd(&cnt[dst[e]], 1);
}

// parallel exclusive "scan" + dis: per-256-chunk local scan + atomic chunk base.
// Bucket ranges only need to be disjoint+sized, not monotone, so atomic ordering is fine.
__global__ __launch_bounds__(256) void k_scan(const int* __restrict__ cnt, int* __restrict__ offset,
                                              int* __restrict__ total, float* __restrict__ dis) {
  __shared__ int red[256];
  __shared__ int sbase;
  const int tid = threadIdx.x;
  const int n = blockIdx.x * 256 + tid;
  const int v = (n < NNODE) ? cnt[n] : 0;
  red[tid] = v; __syncthreads();
  for (int d = 1; d < 256; d <<= 1) {
    const int t = (tid >= d) ? red[tid - d] : 0;
    __syncthreads();
    red[tid] += t;
    __syncthreads();
  }
  if (tid == 255) sbase = atomicAdd(total, red[255]);
  __syncthreads();
  if (n < NNODE) {
    offset[n] = sbase + red[tid] - v;
    dis[n] = rsqrtf((float)(v + 1));
  }
}

__global__ void k_bucket(const int* __restrict__ src, const int* __restrict__ dst,
                         const int* __restrict__ offset, int* __restrict__ fill,
                         int* __restrict__ sorted_src) {
  const int e = blockIdx.x * 256 + threadIdx.x;
  if (e >= NEDGE) return;
  const int t = dst[e];
  const int pos = atomicAdd(&fill[t], 1);
  sorted_src[offset[t] + pos] = src[e];
}

// ---------------- xws = dis[n] * (topo @ gcn_w), stored bf16 (halves gather bytes) ----------------
__global__ __launch_bounds__(256) void k_xw(const float* __restrict__ topo, const float* __restrict__ gcn_w,
                                            const float* __restrict__ dis, __bf16* __restrict__ xws) {
  __shared__ f32x4 w4[4096];             // 64 KB: [d(128)][jq(32)]
  const int tid = threadIdx.x;
  const f32x4* gw4 = (const f32x4*)gcn_w;
  for (int i = tid; i < 4096; i += 256) w4[i] = gw4[i];
  __syncthreads();
  const int n0 = blockIdx.x * 64;
  const int jq = tid & 31, ns = tid >> 5;          // 8 nodes per pass
  for (int pass = 0; pass < 8; ++pass) {
    const int n = n0 + pass * 8 + ns;
    if (n >= NNODE) break;
    const f32x4* tr4 = (const f32x4*)(topo + (size_t)n * 128);
    f32x4 a = {0.f, 0.f, 0.f, 0.f};
    for (int d4 = 0; d4 < 32; ++d4) {
      const f32x4 t = tr4[d4];
      const int base = (d4 << 7) + jq;             // (d4*4)*32 + jq
      #pragma unroll
      for (int m = 0; m < 4; ++m) {
        const f32x4 w = w4[base + m * 32];
        #pragma unroll
        for (int k = 0; k < 4; ++k) a[k] += t[m] * w[k];
      }
    }
    const float dn = dis[n];
    bf16x4 o;
    #pragma unroll
    for (int k = 0; k < 4; ++k) o[k] = (__bf16)(a[k] * dn);
    ((bf16x4*)xws)[(size_t)n * 32 + jq] = o;
  }
}

// ---------------- GCN gather: wave-per-node, bf16 rows, shfl reduce (no LDS/barriers) ----------------
// h[n] = leaky(b + dn*(xws[n] + sum_e xws[src_e]))   [xws pre-scaled by dis]
__global__ __launch_bounds__(256) void k_gather(const int* __restrict__ sorted_src,
                                                const int* __restrict__ offset, const int* __restrict__ cnt,
                                                const float* __restrict__ dis, const __bf16* __restrict__ xws,
                                                const float* __restrict__ gcn_b, __bf16* __restrict__ h) {
  const int wave = threadIdx.x >> 6, lane = threadIdx.x & 63;
  const int n = blockIdx.x * 4 + wave;               // grid 5000 -> n < 20000
  const int slot = lane >> 4, l16 = lane & 15;       // 4 edge slots x 16 dim-groups
  const int e0 = offset[n], ne = cnt[n];
  const bf16x8* x8 = (const bf16x8*)xws;             // row stride 16 (128 dims / 8)
  float a[8];
  if (slot == 0) {
    const bf16x8 v = x8[(size_t)n * 16 + l16];       // self term == xws[n] exactly
    #pragma unroll
    for (int k = 0; k < 8; ++k) a[k] = (float)v[k];
  } else {
    #pragma unroll
    for (int k = 0; k < 8; ++k) a[k] = 0.f;
  }
  for (int e = slot; e < ne; e += 4) {
    const int s = sorted_src[e0 + e];
    const bf16x8 v = x8[(size_t)s * 16 + l16];
    #pragma unroll
    for (int k = 0; k < 8; ++k) a[k] += (float)v[k];
  }
  #pragma unroll
  for (int k = 0; k < 8; ++k) {
    a[k] += __shfl_xor(a[k], 16, 64);
    a[k] += __shfl_xor(a[k], 32, 64);
  }
  if (slot == 0) {
    const float dn = dis[n];
    bf16x8 o;
    #pragma unroll
    for (int k = 0; k < 8; ++k) {
      float t = gcn_b[(l16 << 3) + k] + dn * a[k];
      t = t >= 0.f ? t : 0.2f * t;
      o[k] = (__bf16)t;
    }
    ((bf16x8*)h)[(size_t)n * 16 + l16] = o;
  }
}

__global__ void k_pool_t(const __bf16* __restrict__ h, const int* __restrict__ batch,
                         float* __restrict__ pooled_t) {
  const int d = threadIdx.x;           // 128
  const int n0 = blockIdx.x * 32;
  float run = -FLT_MAX;
  int cur = batch[n0];
  for (int i = 0; i < 32; ++i) {
    const int n = n0 + i;
    const int g = batch[n];
    if (g != cur) {
      atomicMaxF(&pooled_t[cur * 128 + d], run);
      run = -FLT_MAX; cur = g;
    }
    run = fmaxf(run, (float)h[(size_t)n * 128 + d]);
  }
  atomicMaxF(&pooled_t[cur * 128 + d], run);
}

// ---------------- merged FC epilogue: blocks 0..63 vision, 64..127 topo ----------------
__global__ __launch_bounds__(256) void k_fc(const float* __restrict__ pooled_v, const float* __restrict__ fcv_w,
                                            const float* __restrict__ fcv_b,
                                            const float* __restrict__ pooled_t, const float* __restrict__ fct_w,
                                            const float* __restrict__ fct_b,
                                            const float* __restrict__ inv_sigma, float* __restrict__ out) {
  const int tid = threadIdx.x;
  if (blockIdx.x < 64) {
    __shared__ f32x4 xr[128];
    const int b = blockIdx.x;
    if (tid < 128) xr[tid] = ((const f32x4*)pooled_v)[b * 128 + tid];
    __syncthreads();
    const f32x4* wr = (const f32x4*)(fcv_w + (size_t)tid * 512);
    f32x4 a4 = {0.f, 0.f, 0.f, 0.f};
    for (int f = 0; f < 128; ++f) {
      const f32x4 x = xr[f];
      const f32x4 w = wr[f];
      #pragma unroll
      for (int k = 0; k < 4; ++k) a4[k] += x[k] * w[k];
    }
    const float a = a4[0] + a4[1] + a4[2] + a4[3];
    out[b * 256 + tid] = a * inv_sigma[1] + fcv_b[tid];
  } else {
    __shared__ f32x4 xr2[32];
    const int b = blockIdx.x - 64;
    if (tid < 32) xr2[tid] = ((const f32x4*)pooled_t)[b * 32 + tid];
    __syncthreads();
    const f32x4* wr = (const f32x4*)(fct_w + (size_t)tid * 128);
    f32x4 a4 = {0.f, 0.f, 0.f, 0.f};
    for (int f = 0; f < 32; ++f) {
      const f32x4 x = xr2[f];
      const f32x4 w = wr[f];
      #pragma unroll
      for (int k = 0; k < 4; ++k) a4[k] += x[k] * w[k];
    }
    const float a = a4[0] + a4[1] + a4[2] + a4[3];
    out[NB * 256 + b * 256 + tid] = a * inv_sigma[2] + fct_b[tid];
  }
}

extern "C" void kernel_launch(void* const* d_in, const int* in_sizes, int n_in,
                              void* d_out, int out_size, void* d_ws, size_t ws_size,
                              hipStream_t stream) {
  const float* vis    = (const float*)d_in[0];
  const float* topo   = (const float*)d_in[1];
  const int*   eidx   = (const int*)d_in[2];
  const int*   batch  = (const int*)d_in[3];
  const float* conv_w = (const float*)d_in[4];
  const float* conv_b = (const float*)d_in[5];
  const float* conv_u = (const float*)d_in[6];
  const float* fcv_w  = (const float*)d_in[7];
  const float* fcv_b  = (const float*)d_in[8];
  const float* fcv_u  = (const float*)d_in[9];
  const float* gcn_w  = (const float*)d_in[10];
  const float* gcn_b  = (const float*)d_in[11];
  const float* fct_w  = (const float*)d_in[12];
  const float* fct_b  = (const float*)d_in[13];
  const float* fct_u  = (const float*)d_in[14];
  float* out = (float*)d_out;

  char* p = (char*)d_ws;
  float* inv_sigma  = (float*)p; p += 256;
  float* sn_scratch = (float*)p; p += 1796 * 4 + 240;           // v0,v1,v2,ss (pad to 16B)
  float* pooled_v   = (float*)p; p += (size_t)NB * 512 * 4;     // 131072
  float* pooled_t   = (float*)p; p += (size_t)NB * 128 * 4;     // 32768
  int*   cnt        = (int*)p;   p += (size_t)NNODE * 4;
  int*   offset     = (int*)p;   p += (size_t)NNODE * 4;
  int*   fill       = (int*)p;   p += (size_t)NNODE * 4;
  float* dis        = (float*)p; p += (size_t)NNODE * 4;
  int*   ntotal     = (int*)p;   p += 256;
  int*   sorted_src = (int*)p;   p += (size_t)NEDGE * 4;
  __bf16* xws       = (__bf16*)p; p += (size_t)NNODE * 128 * 2 + 256;
  __bf16* h         = (__bf16*)p; p += (size_t)NNODE * 128 * 2 + 256;
  __hip_bfloat16* Bt2 = (__hip_bfloat16*)p; p += (size_t)147456 * 2;
  p = (char*)(((uintptr_t)p + 255) & ~(uintptr_t)255);
  __hip_bfloat16* visT2 = (__hip_bfloat16*)p;                   // 64 MB + tail pad (OOB-read slack)

  // init + spectral norm (parallel 3-stage)
  hipLaunchKernelGGL(k_init,      dim3(128),   dim3(256), 0, stream, pooled_v, pooled_t, cnt, fill, sn_scratch, ntotal);
  hipLaunchKernelGGL(k_sn_v,      dim3(20),    dim3(256), 0, stream, conv_w, conv_u, fcv_w, fcv_u, fct_w, fct_u, sn_scratch);
  hipLaunchKernelGGL(k_sn_w,      dim3(160),   dim3(256), 0, stream, conv_w, fcv_w, fct_w, sn_scratch);
  hipLaunchKernelGGL(k_sn_fin,    dim3(1),     dim3(256), 0, stream, sn_scratch, inv_sigma);
  // vision head
  hipLaunchKernelGGL(k_pack,      dim3(576),   dim3(256), 0, stream, conv_w, inv_sigma, Bt2);
  hipLaunchKernelGGL(k_transpose, dim3(4096),  dim3(256), 0, stream, vis, visT2);
  hipLaunchKernelGGL(k_conv,      dim3(64*31), dim3(256), 0, stream, visT2, Bt2, conv_b, pooled_v);
  // topo head: CSR build + pre-scaled bf16 rows + wave-per-node gather
  hipLaunchKernelGGL(k_deg,       dim3(2500),  dim3(256), 0, stream, eidx + NEDGE, cnt);
  hipLaunchKernelGGL(k_scan,      dim3(79),    dim3(256), 0, stream, cnt, offset, ntotal, dis);
  hipLaunchKernelGGL(k_bucket,    dim3(2500),  dim3(256), 0, stream, eidx, eidx + NEDGE, offset, fill, sorted_src);
  hipLaunchKernelGGL(k_xw,        dim3(313),   dim3(256), 0, stream, topo, gcn_w, dis, xws);
  hipLaunchKernelGGL(k_gather,    dim3(5000),  dim3(256), 0, stream, sorted_src, offset, cnt, dis, xws, gcn_b, h);
  hipLaunchKernelGGL(k_pool_t,    dim3(625),   dim3(128), 0, stream, h, batch, pooled_t);
  // merged FC epilogue (needs pooled_v + pooled_t)
  hipLaunchKernelGGL(k_fc,        dim3(128),   dim3(256), 0, stream, pooled_v, fcv_w, fcv_b, pooled_t, fct_w, fct_b, inv_sigma, out);
}

// Round 5
// 546.331 us; speedup vs baseline: 1.1850x; 1.0151x over previous
//
#include <hip/hip_runtime.h>
#include <hip/hip_bf16.h>
#include <float.h>
#include <stdint.h>

// Problem constants
#define NB   64      // batch / num graphs
#define CD   128     // channels / dims
#define OUTD 256
#define NNODE 20000
#define NEDGE 640000

typedef __bf16 bf16x8 __attribute__((ext_vector_type(8)));
typedef __bf16 bf16x4 __attribute__((ext_vector_type(4)));
typedef float  f32x4  __attribute__((ext_vector_type(4)));

__device__ inline void gl_lds16(const void* g, void* l) {
  __builtin_amdgcn_global_load_lds(
      (const __attribute__((address_space(1))) void*)g,
      (__attribute__((address_space(3))) void*)l, 16, 0, 0);
}

// float atomic max via signed/unsigned int monotonic trick (works for mixed signs)
__device__ inline void atomicMaxF(float* addr, float val) {
  if (val >= 0.f) atomicMax((int*)addr, __float_as_int(val));
  else            atomicMin((unsigned int*)addr, __float_as_uint(val));
}

// ---------------- init: pooled buffers (-FLT_MAX), CSR counters (=0), SN scratch (=0) ----------------
// sn_scratch layout: [0..1151]=v0, [1152..1663]=v1, [1664..1791]=v2, [1792..1795]=ss
__global__ void k_init(float* __restrict__ pooled_v, float* __restrict__ pooled_t,
                       int* __restrict__ cnt, int* __restrict__ fill,
                       float* __restrict__ sn_scratch, int* __restrict__ ntotal) {
  const int i = blockIdx.x * 256 + threadIdx.x;   // grid covers 32768
  if (i < NB * CD * 4) pooled_v[i] = -FLT_MAX;
  if (i < NB * CD)     pooled_t[i] = -FLT_MAX;
  if (i < NNODE)       { cnt[i] = 0; fill[i] = 0; }
  if (i < 1796)        sn_scratch[i] = 0.0f;
  if (i == 0)          *ntotal = 0;
}

// ---------------- SN stage 1: v = W^T u, 32-row chunks, coalesced, atomicAdd per column ----------------
__global__ __launch_bounds__(256) void k_sn_v(const float* __restrict__ conv_w, const float* __restrict__ conv_u,
                                              const float* __restrict__ fcv_w,  const float* __restrict__ fcv_u,
                                              const float* __restrict__ fct_w,  const float* __restrict__ fct_u,
                                              float* __restrict__ sn) {
  const int bb = blockIdx.x;       // 0..19
  const float* W; const float* u; float* v; int C; int r0;
  if (bb < 4)       { W = conv_w; u = conv_u; v = sn;        C = 1152; r0 = bb * 32; }
  else if (bb < 12) { W = fcv_w;  u = fcv_u;  v = sn + 1152; C = 512;  r0 = (bb - 4) * 32; }
  else              { W = fct_w;  u = fct_u;  v = sn + 1664; C = 128;  r0 = (bb - 12) * 32; }
  const int tid = threadIdx.x;
  float acc[5] = {0.f, 0.f, 0.f, 0.f, 0.f};
  for (int i = r0; i < r0 + 32; ++i) {
    const float ui = u[i];
    const float* row = W + (size_t)i * C;
    #pragma unroll
    for (int t = 0; t < 5; ++t) {
      const int j = tid + t * 256;
      if (j < C) acc[t] += ui * row[j];
    }
  }
  #pragma unroll
  for (int t = 0; t < 5; ++t) {
    const int j = tid + t * 256;
    if (j < C) atomicAdd(&v[j], acc[t]);
  }
}

// ---------------- SN stage 2: ss[m] = ||W v||^2, one wave per row ----------------
__global__ __launch_bounds__(256) void k_sn_w(const float* __restrict__ conv_w,
                                              const float* __restrict__ fcv_w,
                                              const float* __restrict__ fct_w,
                                              float* __restrict__ sn) {
  const int gw = blockIdx.x * 4 + (threadIdx.x >> 6);   // global wave id, 0..639
  const int lane = threadIdx.x & 63;
  const float* W; const float* v; int C, m, row;
  if (gw < 128)      { W = conv_w; v = sn;        C = 1152; m = 0; row = gw; }
  else if (gw < 384) { W = fcv_w;  v = sn + 1152; C = 512;  m = 1; row = gw - 128; }
  else               { W = fct_w;  v = sn + 1664; C = 128;  m = 2; row = gw - 384; }
  const float* wr = W + (size_t)row * C;
  float y = 0.f;
  for (int c = lane; c < C; c += 64) y += wr[c] * v[c];
  #pragma unroll
  for (int s = 32; s > 0; s >>= 1) y += __shfl_xor(y, s, 64);
  if (lane == 0) atomicAdd(&sn[1792 + m], y * y);
}

// ---------------- SN stage 3: inv_sigma[m] = (||v||+eps)/||Wv|| ----------------
__global__ __launch_bounds__(256) void k_sn_fin(const float* __restrict__ sn, float* __restrict__ inv_sigma) {
  __shared__ float red[256];
  const int tid = threadIdx.x;
  const int off[4] = {0, 1152, 1664, 1792};
  for (int m = 0; m < 3; ++m) {
    const int C = off[m + 1] - off[m];
    float ss = 0.f;
    for (int j = tid; j < C; j += 256) { const float a = sn[off[m] + j]; ss += a * a; }
    red[tid] = ss; __syncthreads();
    for (int s = 128; s > 0; s >>= 1) { if (tid < s) red[tid] += red[tid + s]; __syncthreads(); }
    if (tid == 0) inv_sigma[m] = (sqrtf(red[0]) + 1e-12f) / sqrtf(sn[1792 + m]);
    __syncthreads();
  }
}

// ---------------- fused prep: transpose (blocks 0..4095) + pack (4096..4671) + deg (4672..7171) ----------------
// All three are mutually independent; pack needs inv_sigma (after k_sn_fin), deg needs cnt zeroed (k_init).
__global__ __launch_bounds__(256) void k_prep(const float* __restrict__ vis, __hip_bfloat16* __restrict__ visT2,
                                              const float* __restrict__ conv_w, const float* __restrict__ inv_sigma,
                                              __hip_bfloat16* __restrict__ Bt2,
                                              const int* __restrict__ dst, int* __restrict__ cnt) {
  __shared__ float tile[8192];            // [c(128)][x(64)] (transpose branch only)
  const int bid = blockIdx.x;
  const int t = threadIdx.x;
  if (bid < 4096) {
    // NCHW f32 -> tiled bf16: visT2[b][y][g=c/8][x(64)][c8(8)]; f32x4 loads (R7: was 32 scalar loads)
    const int b = bid >> 6, y = bid & 63;
    const int c0 = t >> 4, x4 = (t & 15) << 2;
    const float* src = vis + (size_t)b * 524288 + y * 64;
    #pragma unroll
    for (int i = 0; i < 8; ++i) {
      const int c = i * 16 + c0;
      *(f32x4*)&tile[c * 64 + x4] = *(const f32x4*)(src + (size_t)c * 4096 + x4);
    }
    __syncthreads();
    bf16x8* dstv = (bf16x8*)(visT2 + ((size_t)bid << 13));   // bid*16*512 elems
    #pragma unroll
    for (int k = 0; k < 4; ++k) {
      const int j = k * 256 + t;            // chunk: g = j>>6, x = j&63
      const int g = j >> 6, x = j & 63;
      union { bf16x8 v; __hip_bfloat16 h[8]; } u;
      #pragma unroll
      for (int cc = 0; cc < 8; ++cc)
        u.h[cc] = __float2bfloat16(tile[(g * 8 + cc) * 64 + x]);
      dstv[j] = u.v;
    }
  } else if (bid < 4672) {
    // Bt2[tap(9)][halfk(2)][sub(8)][n(128)][c8(8)] = conv_w[n][ci=hk*64+s*8+j][tap] / sigma
    const int tt = (bid - 4096) * 256 + t;
    if (tt < 147456) {
      const int j = tt & 7, n = (tt >> 3) & 127, s = (tt >> 10) & 7, hk = (tt >> 13) & 1, tap = tt >> 14;
      const int ci = hk * 64 + s * 8 + j;
      Bt2[tt] = __float2bfloat16(conv_w[n * 1152 + ci * 9 + tap] * inv_sigma[0]);
    }
  } else {
    const int e = (bid - 4672) * 256 + t;
    if (e < NEDGE) atomicAdd(&cnt[dst[e]], 1);
  }
}

// ---------------- fused conv3x3 + bias + leaky + 31x31 maxpool (implicit GEMM, bf16 MFMA) ----------------
// R4 structure (proven 93us) + bijective XCD swizzle (1984 = 8 x 248: same-batch blocks share XCD L2).
__global__ __launch_bounds__(256, 4) void k_conv(const __hip_bfloat16* __restrict__ visT2,
                                                 const __hip_bfloat16* __restrict__ Bt2,
                                                 const float* __restrict__ conv_b,
                                                 float* __restrict__ pooled_v) {
  __shared__ bf16x8 lds_a[1024];   // 16 KB  [sub(8)][m(128)]
  __shared__ bf16x8 lds_b[1024];   // 16 KB  [sub(8)][n(128)]
  const int bx = (blockIdx.x & 7) * 248 + (blockIdx.x >> 3);   // XCD swizzle, bijective on 1984
  const int b = bx / 31;
  const int y0 = (bx - b * 31) * 2;
  const int tid = threadIdx.x;
  const int wave = tid >> 6, lane = tid & 63;
  const int quad = lane >> 4, l15 = lane & 15;

  f32x4 acc[8][2];
  #pragma unroll
  for (int i = 0; i < 8; ++i) {
    acc[i][0] = f32x4{0.f, 0.f, 0.f, 0.f};
    acc[i][1] = f32x4{0.f, 0.f, 0.f, 0.f};
  }

  const __hip_bfloat16* vb = visT2 + ((size_t)b << 19);   // b*64*16*512
  const int s0 = wave << 1;                 // this wave stages subchunks s0, s0+1
  bf16x8* ldsA0 = &lds_a[s0 << 7];
  bf16x8* ldsB0 = &lds_b[s0 << 7];
  const int lane8 = lane << 3;

  for (int ky = 0; ky < 3; ++ky) {
    for (int kx = 0; kx < 3; ++kx) {
      const int tap = ky * 3 + kx;
      #pragma unroll
      for (int hk = 0; hk < 2; ++hk) {
        // A: visT2 row-group (y, g=hk*8+s); kx shift = +kx*8 elems; lanes contiguous.
        const __hip_bfloat16* a0p = vb + ((size_t)(((y0 + ky) << 4) + (hk << 3) + s0) << 9) + (kx << 3) + lane8;
        const __hip_bfloat16* a1p = vb + ((size_t)(((y0 + 1 + ky) << 4) + (hk << 3) + s0) << 9) + (kx << 3) + lane8;
        const __hip_bfloat16* bp  = Bt2 + (((size_t)(((tap << 1) + hk) << 3) + s0) << 10) + lane8;
        gl_lds16(a0p,        ldsA0);         // sub s0, m 0..63   (row0)
        gl_lds16(a1p,        ldsA0 + 64);    // sub s0, m 64..127 (row1)
        gl_lds16(a0p + 512,  ldsA0 + 128);   // sub s0+1, row0
        gl_lds16(a1p + 512,  ldsA0 + 192);   // sub s0+1, row1
        gl_lds16(bp,         ldsB0);         // sub s0, n 0..63
        gl_lds16(bp + 512,   ldsB0 + 64);    // sub s0, n 64..127
        gl_lds16(bp + 1024,  ldsB0 + 128);   // sub s0+1, n 0..63
        gl_lds16(bp + 1536,  ldsB0 + 192);   // sub s0+1, n 64..127
        __syncthreads();
        const bf16x8 b00 = lds_b[(quad << 7) + (wave << 5) + l15];
        const bf16x8 b01 = lds_b[(quad << 7) + (wave << 5) + 16 + l15];
        const bf16x8 b10 = lds_b[((4 + quad) << 7) + (wave << 5) + l15];
        const bf16x8 b11 = lds_b[((4 + quad) << 7) + (wave << 5) + 16 + l15];
        #pragma unroll
        for (int mt = 0; mt < 8; ++mt) {
          const bf16x8 a0 = lds_a[(quad << 7) + (mt << 4) + l15];
          const bf16x8 a1 = lds_a[((4 + quad) << 7) + (mt << 4) + l15];
          acc[mt][0] = __builtin_amdgcn_mfma_f32_16x16x32_bf16(a0, b00, acc[mt][0], 0, 0, 0);
          acc[mt][1] = __builtin_amdgcn_mfma_f32_16x16x32_bf16(a0, b01, acc[mt][1], 0, 0, 0);
          acc[mt][0] = __builtin_amdgcn_mfma_f32_16x16x32_bf16(a1, b10, acc[mt][0], 0, 0, 0);
          acc[mt][1] = __builtin_amdgcn_mfma_f32_16x16x32_bf16(a1, b11, acc[mt][1], 0, 0, 0);
        }
        __syncthreads();
      }
    }
  }

  // epilogue: bias + leaky + pool-max. C layout: n = nbase + l15, m = mt*16 + quad*4 + r.
  const float cb0 = conv_b[(wave << 5) + l15];
  const float cb1 = conv_b[(wave << 5) + 16 + l15];
  float pmax[2][2][2];
  #pragma unroll
  for (int i = 0; i < 8; ++i) (&pmax[0][0][0])[i] = -FLT_MAX;

  #pragma unroll
  for (int mt = 0; mt < 8; ++mt) {
    const int py = (y0 + (mt >> 2)) >= 31 ? 1 : 0;
    #pragma unroll
    for (int r = 0; r < 4; ++r) {
      const int x = ((mt & 3) << 4) + (quad << 2) + r;
      if (x < 62) {
        const int px = x >= 31 ? 1 : 0;
        float v0 = acc[mt][0][r] + cb0;  v0 = v0 >= 0.f ? v0 : 0.2f * v0;
        float v1 = acc[mt][1][r] + cb1;  v1 = v1 >= 0.f ? v1 : 0.2f * v1;
        pmax[0][py][px] = fmaxf(pmax[0][py][px], v0);
        pmax[1][py][px] = fmaxf(pmax[1][py][px], v1);
      }
    }
  }
  #pragma unroll
  for (int nt = 0; nt < 2; ++nt)
    #pragma unroll
    for (int py = 0; py < 2; ++py)
      #pragma unroll
      for (int px = 0; px < 2; ++px) {
        float v = pmax[nt][py][px];
        v = fmaxf(v, __shfl_xor(v, 16, 64));
        v = fmaxf(v, __shfl_xor(v, 32, 64));
        if (quad == 0) {
          const int n = (wave << 5) + (nt << 4) + l15;
          atomicMaxF(&pooled_v[(size_t)b * 512 + n * 4 + py * 2 + px], v);
        }
      }
}

// ---------------- fused scan (blocks 0..78) + xw (79..391) ----------------
// scan: per-256-chunk local scan + atomic chunk base (bucket ranges need disjointness, not order).
// xw:   xws = dis[n] * (topo @ gcn_w), bf16; dis recomputed from cnt (no scan dependency).
__global__ __launch_bounds__(256) void k_scan_xw(const int* __restrict__ cnt, int* __restrict__ offset,
                                                 int* __restrict__ total, float* __restrict__ dis,
                                                 const float* __restrict__ topo, const float* __restrict__ gcn_w,
                                                 __bf16* __restrict__ xws) {
  __shared__ f32x4 w4[4096];             // 64 KB: xw weights [d(128)][jq(32)]; scan reuses as int scratch
  __shared__ int sbase;
  const int tid = threadIdx.x;
  if (blockIdx.x < 79) {
    int* red = (int*)w4;
    const int n = blockIdx.x * 256 + tid;
    const int v = (n < NNODE) ? cnt[n] : 0;
    red[tid] = v; __syncthreads();
    for (int d = 1; d < 256; d <<= 1) {
      const int t = (tid >= d) ? red[tid - d] : 0;
      __syncthreads();
      red[tid] += t;
      __syncthreads();
    }
    if (tid == 255) sbase = atomicAdd(total, red[255]);
    __syncthreads();
    if (n < NNODE) {
      offset[n] = sbase + red[tid] - v;
      dis[n] = rsqrtf((float)(v + 1));
    }
  } else {
    const f32x4* gw4 = (const f32x4*)gcn_w;
    for (int i = tid; i < 4096; i += 256) w4[i] = gw4[i];
    __syncthreads();
    const int n0 = (blockIdx.x - 79) * 64;
    const int jq = tid & 31, ns = tid >> 5;          // 8 nodes per pass
    for (int pass = 0; pass < 8; ++pass) {
      const int n = n0 + pass * 8 + ns;
      if (n >= NNODE) break;
      const f32x4* tr4 = (const f32x4*)(topo + (size_t)n * 128);
      f32x4 a = {0.f, 0.f, 0.f, 0.f};
      for (int d4 = 0; d4 < 32; ++d4) {
        const f32x4 t = tr4[d4];
        const int base = (d4 << 7) + jq;             // (d4*4)*32 + jq
        #pragma unroll
        for (int m = 0; m < 4; ++m) {
          const f32x4 w = w4[base + m * 32];
          #pragma unroll
          for (int k = 0; k < 4; ++k) a[k] += t[m] * w[k];
        }
      }
      const float dn = rsqrtf((float)(cnt[n] + 1));
      bf16x4 o;
      #pragma unroll
      for (int k = 0; k < 4; ++k) o[k] = (__bf16)(a[k] * dn);
      ((bf16x4*)xws)[(size_t)n * 32 + jq] = o;
    }
  }
}

__global__ void k_bucket(const int* __restrict__ src, const int* __restrict__ dst,
                         const int* __restrict__ offset, int* __restrict__ fill,
                         int* __restrict__ sorted_src) {
  const int e = blockIdx.x * 256 + threadIdx.x;
  if (e >= NEDGE) return;
  const int t = dst[e];
  const int pos = atomicAdd(&fill[t], 1);
  sorted_src[offset[t] + pos] = src[e];
}

// ---------------- GCN gather: wave-per-node, bf16 rows, shfl reduce (no LDS/barriers) ----------------
// h[n] = leaky(b + dn*(xws[n] + sum_e xws[src_e]))   [xws pre-scaled by dis]
__global__ __launch_bounds__(256) void k_gather(const int* __restrict__ sorted_src,
                                                const int* __restrict__ offset, const int* __restrict__ cnt,
                                                const float* __restrict__ dis, const __bf16* __restrict__ xws,
                                                const float* __restrict__ gcn_b, __bf16* __restrict__ h) {
  const int wave = threadIdx.x >> 6, lane = threadIdx.x & 63;
  const int n = blockIdx.x * 4 + wave;               // grid 5000 -> n < 20000
  const int slot = lane >> 4, l16 = lane & 15;       // 4 edge slots x 16 dim-groups
  const int e0 = offset[n], ne = cnt[n];
  const bf16x8* x8 = (const bf16x8*)xws;             // row stride 16 (128 dims / 8)
  float a[8];
  if (slot == 0) {
    const bf16x8 v = x8[(size_t)n * 16 + l16];       // self term == xws[n] exactly
    #pragma unroll
    for (int k = 0; k < 8; ++k) a[k] = (float)v[k];
  } else {
    #pragma unroll
    for (int k = 0; k < 8; ++k) a[k] = 0.f;
  }
  for (int e = slot; e < ne; e += 4) {
    const int s = sorted_src[e0 + e];
    const bf16x8 v = x8[(size_t)s * 16 + l16];
    #pragma unroll
    for (int k = 0; k < 8; ++k) a[k] += (float)v[k];
  }
  #pragma unroll
  for (int k = 0; k < 8; ++k) {
    a[k] += __shfl_xor(a[k], 16, 64);
    a[k] += __shfl_xor(a[k], 32, 64);
  }
  if (slot == 0) {
    const float dn = dis[n];
    bf16x8 o;
    #pragma unroll
    for (int k = 0; k < 8; ++k) {
      float t = gcn_b[(l16 << 3) + k] + dn * a[k];
      t = t >= 0.f ? t : 0.2f * t;
      o[k] = (__bf16)t;
    }
    ((bf16x8*)h)[(size_t)n * 16 + l16] = o;
  }
}

__global__ void k_pool_t(const __bf16* __restrict__ h, const int* __restrict__ batch,
                         float* __restrict__ pooled_t) {
  const int d = threadIdx.x;           // 128
  const int n0 = blockIdx.x * 32;
  float run = -FLT_MAX;
  int cur = batch[n0];
  for (int i = 0; i < 32; ++i) {
    const int n = n0 + i;
    const int g = batch[n];
    if (g != cur) {
      atomicMaxF(&pooled_t[cur * 128 + d], run);
      run = -FLT_MAX; cur = g;
    }
    run = fmaxf(run, (float)h[(size_t)n * 128 + d]);
  }
  atomicMaxF(&pooled_t[cur * 128 + d], run);
}

// ---------------- merged FC epilogue: blocks 0..63 vision, 64..127 topo ----------------
__global__ __launch_bounds__(256) void k_fc(const float* __restrict__ pooled_v, const float* __restrict__ fcv_w,
                                            const float* __restrict__ fcv_b,
                                            const float* __restrict__ pooled_t, const float* __restrict__ fct_w,
                                            const float* __restrict__ fct_b,
                                            const float* __restrict__ inv_sigma, float* __restrict__ out) {
  const int tid = threadIdx.x;
  if (blockIdx.x < 64) {
    __shared__ f32x4 xr[128];
    const int b = blockIdx.x;
    if (tid < 128) xr[tid] = ((const f32x4*)pooled_v)[b * 128 + tid];
    __syncthreads();
    const f32x4* wr = (const f32x4*)(fcv_w + (size_t)tid * 512);
    f32x4 a4 = {0.f, 0.f, 0.f, 0.f};
    for (int f = 0; f < 128; ++f) {
      const f32x4 x = xr[f];
      const f32x4 w = wr[f];
      #pragma unroll
      for (int k = 0; k < 4; ++k) a4[k] += x[k] * w[k];
    }
    const float a = a4[0] + a4[1] + a4[2] + a4[3];
    out[b * 256 + tid] = a * inv_sigma[1] + fcv_b[tid];
  } else {
    __shared__ f32x4 xr2[32];
    const int b = blockIdx.x - 64;
    if (tid < 32) xr2[tid] = ((const f32x4*)pooled_t)[b * 32 + tid];
    __syncthreads();
    const f32x4* wr = (const f32x4*)(fct_w + (size_t)tid * 128);
    f32x4 a4 = {0.f, 0.f, 0.f, 0.f};
    for (int f = 0; f < 32; ++f) {
      const f32x4 x = xr2[f];
      const f32x4 w = wr[f];
      #pragma unroll
      for (int k = 0; k < 4; ++k) a4[k] += x[k] * w[k];
    }
    const float a = a4[0] + a4[1] + a4[2] + a4[3];
    out[NB * 256 + b * 256 + tid] = a * inv_sigma[2] + fct_b[tid];
  }
}

extern "C" void kernel_launch(void* const* d_in, const int* in_sizes, int n_in,
                              void* d_out, int out_size, void* d_ws, size_t ws_size,
                              hipStream_t stream) {
  const float* vis    = (const float*)d_in[0];
  const float* topo   = (const float*)d_in[1];
  const int*   eidx   = (const int*)d_in[2];
  const int*   batch  = (const int*)d_in[3];
  const float* conv_w = (const float*)d_in[4];
  const float* conv_b = (const float*)d_in[5];
  const float* conv_u = (const float*)d_in[6];
  const float* fcv_w  = (const float*)d_in[7];
  const float* fcv_b  = (const float*)d_in[8];
  const float* fcv_u  = (const float*)d_in[9];
  const float* gcn_w  = (const float*)d_in[10];
  const float* gcn_b  = (const float*)d_in[11];
  const float* fct_w  = (const float*)d_in[12];
  const float* fct_b  = (const float*)d_in[13];
  const float* fct_u  = (const float*)d_in[14];
  float* out = (float*)d_out;

  char* p = (char*)d_ws;
  float* inv_sigma  = (float*)p; p += 256;
  float* sn_scratch = (float*)p; p += 1796 * 4 + 240;           // v0,v1,v2,ss (pad to 16B)
  float* pooled_v   = (float*)p; p += (size_t)NB * 512 * 4;     // 131072
  float* pooled_t   = (float*)p; p += (size_t)NB * 128 * 4;     // 32768
  int*   cnt        = (int*)p;   p += (size_t)NNODE * 4;
  int*   offset     = (int*)p;   p += (size_t)NNODE * 4;
  int*   fill       = (int*)p;   p += (size_t)NNODE * 4;
  float* dis        = (float*)p; p += (size_t)NNODE * 4;
  int*   ntotal     = (int*)p;   p += 256;
  int*   sorted_src = (int*)p;   p += (size_t)NEDGE * 4;
  __bf16* xws       = (__bf16*)p; p += (size_t)NNODE * 128 * 2 + 256;
  __bf16* h         = (__bf16*)p; p += (size_t)NNODE * 128 * 2 + 256;
  __hip_bfloat16* Bt2 = (__hip_bfloat16*)p; p += (size_t)147456 * 2;
  p = (char*)(((uintptr_t)p + 255) & ~(uintptr_t)255);
  __hip_bfloat16* visT2 = (__hip_bfloat16*)p;                   // 64 MB + tail pad (OOB-read slack)

  // init + spectral norm (parallel 3-stage)
  hipLaunchKernelGGL(k_init,    dim3(128),  dim3(256), 0, stream, pooled_v, pooled_t, cnt, fill, sn_scratch, ntotal);
  hipLaunchKernelGGL(k_sn_v,    dim3(20),   dim3(256), 0, stream, conv_w, conv_u, fcv_w, fcv_u, fct_w, fct_u, sn_scratch);
  hipLaunchKernelGGL(k_sn_w,    dim3(160),  dim3(256), 0, stream, conv_w, fcv_w, fct_w, sn_scratch);
  hipLaunchKernelGGL(k_sn_fin,  dim3(1),    dim3(256), 0, stream, sn_scratch, inv_sigma);
  // fused prep: transpose + pack + deg
  hipLaunchKernelGGL(k_prep,    dim3(7172), dim3(256), 0, stream, vis, visT2, conv_w, inv_sigma, Bt2, eidx + NEDGE, cnt);
  // vision head main
  hipLaunchKernelGGL(k_conv,    dim3(64*31), dim3(256), 0, stream, visT2, Bt2, conv_b, pooled_v);
  // topo head: scan+xw fused, then bucket, gather, pool
  hipLaunchKernelGGL(k_scan_xw, dim3(392),  dim3(256), 0, stream, cnt, offset, ntotal, dis, topo, gcn_w, xws);
  hipLaunchKernelGGL(k_bucket,  dim3(2500), dim3(256), 0, stream, eidx, eidx + NEDGE, offset, fill, sorted_src);
  hipLaunchKernelGGL(k_gather,  dim3(5000), dim3(256), 0, stream, sorted_src, offset, cnt, dis, xws, gcn_b, h);
  hipLaunchKernelGGL(k_pool_t,  dim3(625),  dim3(128), 0, stream, h, batch, pooled_t);
  // merged FC epilogue (needs pooled_v + pooled_t)
  hipLaunchKernelGGL(k_fc,      dim3(128),  dim3(256), 0, stream, pooled_v, fcv_w, fcv_b, pooled_t, fct_w, fct_b, inv_sigma, out);
}

// Round 6
// 489.034 us; speedup vs baseline: 1.3239x; 1.1172x over previous
//
#include <hip/hip_runtime.h>
#include <hip/hip_bf16.h>
#include <float.h>
#include <stdint.h>

// Problem constants
#define NB   64      // batch / num graphs
#define CD   128     // channels / dims
#define OUTD 256
#define NNODE 20000
#define NEDGE 640000

typedef __bf16 bf16x8 __attribute__((ext_vector_type(8)));
typedef __bf16 bf16x4 __attribute__((ext_vector_type(4)));
typedef float  f32x4  __attribute__((ext_vector_type(4)));

__device__ inline void gl_lds16(const void* g, void* l) {
  __builtin_amdgcn_global_load_lds(
      (const __attribute__((address_space(1))) void*)g,
      (__attribute__((address_space(3))) void*)l, 16, 0, 0);
}

// float atomic max via signed/unsigned int monotonic trick (works for mixed signs)
__device__ inline void atomicMaxF(float* addr, float val) {
  if (val >= 0.f) atomicMax((int*)addr, __float_as_int(val));
  else            atomicMin((unsigned int*)addr, __float_as_uint(val));
}

// ---------------- init: pooled buffers (-FLT_MAX), CSR counters (=0), SN scratch (=0) ----------------
// sn_scratch layout: [0..1151]=v0, [1152..1663]=v1, [1664..1791]=v2, [1792..1795]=ss
__global__ void k_init(float* __restrict__ pooled_v, float* __restrict__ pooled_t,
                       int* __restrict__ cnt, int* __restrict__ fill,
                       float* __restrict__ sn_scratch, int* __restrict__ ntotal) {
  const int i = blockIdx.x * 256 + threadIdx.x;   // grid covers 32768
  if (i < NB * CD * 4) pooled_v[i] = -FLT_MAX;
  if (i < NB * CD)     pooled_t[i] = -FLT_MAX;
  if (i < NNODE)       { cnt[i] = 0; fill[i] = 0; }
  if (i < 1796)        sn_scratch[i] = 0.0f;
  if (i == 0)          *ntotal = 0;
}

// ---------------- SN stage 1: v = W^T u, 8-row chunks (80 blocks: was 20 -> latency-exposed) ----------------
__global__ __launch_bounds__(256) void k_sn_v(const float* __restrict__ conv_w, const float* __restrict__ conv_u,
                                              const float* __restrict__ fcv_w,  const float* __restrict__ fcv_u,
                                              const float* __restrict__ fct_w,  const float* __restrict__ fct_u,
                                              float* __restrict__ sn) {
  const int bb = blockIdx.x;       // 0..79
  const float* W; const float* u; float* v; int C; int r0;
  if (bb < 16)      { W = conv_w; u = conv_u; v = sn;        C = 1152; r0 = bb * 8; }
  else if (bb < 48) { W = fcv_w;  u = fcv_u;  v = sn + 1152; C = 512;  r0 = (bb - 16) * 8; }
  else              { W = fct_w;  u = fct_u;  v = sn + 1664; C = 128;  r0 = (bb - 48) * 8; }
  const int tid = threadIdx.x;
  float acc[5] = {0.f, 0.f, 0.f, 0.f, 0.f};
  for (int i = r0; i < r0 + 8; ++i) {
    const float ui = u[i];
    const float* row = W + (size_t)i * C;
    #pragma unroll
    for (int t = 0; t < 5; ++t) {
      const int j = tid + t * 256;
      if (j < C) acc[t] += ui * row[j];
    }
  }
  #pragma unroll
  for (int t = 0; t < 5; ++t) {
    const int j = tid + t * 256;
    if (j < C) atomicAdd(&v[j], acc[t]);
  }
}

// ---------------- SN stage 2: ss[m] = ||W v||^2, one wave per row ----------------
__global__ __launch_bounds__(256) void k_sn_w(const float* __restrict__ conv_w,
                                              const float* __restrict__ fcv_w,
                                              const float* __restrict__ fct_w,
                                              float* __restrict__ sn) {
  const int gw = blockIdx.x * 4 + (threadIdx.x >> 6);   // global wave id, 0..639
  const int lane = threadIdx.x & 63;
  const float* W; const float* v; int C, m, row;
  if (gw < 128)      { W = conv_w; v = sn;        C = 1152; m = 0; row = gw; }
  else if (gw < 384) { W = fcv_w;  v = sn + 1152; C = 512;  m = 1; row = gw - 128; }
  else               { W = fct_w;  v = sn + 1664; C = 128;  m = 2; row = gw - 384; }
  const float* wr = W + (size_t)row * C;
  float y = 0.f;
  for (int c = lane; c < C; c += 64) y += wr[c] * v[c];
  #pragma unroll
  for (int s = 32; s > 0; s >>= 1) y += __shfl_xor(y, s, 64);
  if (lane == 0) atomicAdd(&sn[1792 + m], y * y);
}

// ---------------- SN stage 3: inv_sigma[m] = (||v||+eps)/||Wv|| ----------------
__global__ __launch_bounds__(256) void k_sn_fin(const float* __restrict__ sn, float* __restrict__ inv_sigma) {
  __shared__ float red[256];
  const int tid = threadIdx.x;
  const int off[4] = {0, 1152, 1664, 1792};
  for (int m = 0; m < 3; ++m) {
    const int C = off[m + 1] - off[m];
    float ss = 0.f;
    for (int j = tid; j < C; j += 256) { const float a = sn[off[m] + j]; ss += a * a; }
    red[tid] = ss; __syncthreads();
    for (int s = 128; s > 0; s >>= 1) { if (tid < s) red[tid] += red[tid + s]; __syncthreads(); }
    if (tid == 0) inv_sigma[m] = (sqrtf(red[0]) + 1e-12f) / sqrtf(sn[1792 + m]);
    __syncthreads();
  }
}

// ---------------- fused prep: transpose (blocks 0..4095) + pack (4096..4671) + deg (4672..7171) ----------------
// All three are mutually independent; pack needs inv_sigma (after k_sn_fin), deg needs cnt zeroed (k_init).
__global__ __launch_bounds__(256) void k_prep(const float* __restrict__ vis, __hip_bfloat16* __restrict__ visT2,
                                              const float* __restrict__ conv_w, const float* __restrict__ inv_sigma,
                                              __hip_bfloat16* __restrict__ Bt2,
                                              const int* __restrict__ dst, int* __restrict__ cnt) {
  __shared__ float tile[8192];            // [c(128)][x(64)] (transpose branch only)
  const int bid = blockIdx.x;
  const int t = threadIdx.x;
  if (bid < 4096) {
    // NCHW f32 -> tiled bf16: visT2[b][y][g=c/8][x(64)][c8(8)]; f32x4 loads
    const int b = bid >> 6, y = bid & 63;
    const int c0 = t >> 4, x4 = (t & 15) << 2;
    const float* src = vis + (size_t)b * 524288 + y * 64;
    #pragma unroll
    for (int i = 0; i < 8; ++i) {
      const int c = i * 16 + c0;
      *(f32x4*)&tile[c * 64 + x4] = *(const f32x4*)(src + (size_t)c * 4096 + x4);
    }
    __syncthreads();
    bf16x8* dstv = (bf16x8*)(visT2 + ((size_t)bid << 13));   // bid*16*512 elems
    #pragma unroll
    for (int k = 0; k < 4; ++k) {
      const int j = k * 256 + t;            // chunk: g = j>>6, x = j&63
      const int g = j >> 6, x = j & 63;
      union { bf16x8 v; __hip_bfloat16 h[8]; } u;
      #pragma unroll
      for (int cc = 0; cc < 8; ++cc)
        u.h[cc] = __float2bfloat16(tile[(g * 8 + cc) * 64 + x]);
      dstv[j] = u.v;
    }
  } else if (bid < 4672) {
    // Bt2[tap(9)][halfk(2)][sub(8)][n(128)][c8(8)] = conv_w[n][ci=hk*64+s*8+j][tap] / sigma
    const int tt = (bid - 4096) * 256 + t;
    if (tt < 147456) {
      const int j = tt & 7, n = (tt >> 3) & 127, s = (tt >> 10) & 7, hk = (tt >> 13) & 1, tap = tt >> 14;
      const int ci = hk * 64 + s * 8 + j;
      Bt2[tt] = __float2bfloat16(conv_w[n * 1152 + ci * 9 + tap] * inv_sigma[0]);
    }
  } else {
    const int e = (bid - 4672) * 256 + t;
    if (e < NEDGE) atomicAdd(&cnt[dst[e]], 1);
  }
}

// ---------------- fused conv3x3 + bias + leaky + 31x31 maxpool (implicit GEMM, bf16 MFMA) ----------------
// R4 structure (proven 93us). R8's XCD swizzle REGRESSED (93->114us): k_conv is schedule-bound at
// 24% HBM, so the -31MB fetch bought nothing while same-batch concentration serialized one L2.
__global__ __launch_bounds__(256, 4) void k_conv(const __hip_bfloat16* __restrict__ visT2,
                                                 const __hip_bfloat16* __restrict__ Bt2,
                                                 const float* __restrict__ conv_b,
                                                 float* __restrict__ pooled_v) {
  __shared__ bf16x8 lds_a[1024];   // 16 KB  [sub(8)][m(128)]
  __shared__ bf16x8 lds_b[1024];   // 16 KB  [sub(8)][n(128)]
  const int bx = blockIdx.x;
  const int b = bx / 31;
  const int y0 = (bx - b * 31) * 2;
  const int tid = threadIdx.x;
  const int wave = tid >> 6, lane = tid & 63;
  const int quad = lane >> 4, l15 = lane & 15;

  f32x4 acc[8][2];
  #pragma unroll
  for (int i = 0; i < 8; ++i) {
    acc[i][0] = f32x4{0.f, 0.f, 0.f, 0.f};
    acc[i][1] = f32x4{0.f, 0.f, 0.f, 0.f};
  }

  const __hip_bfloat16* vb = visT2 + ((size_t)b << 19);   // b*64*16*512
  const int s0 = wave << 1;                 // this wave stages subchunks s0, s0+1
  bf16x8* ldsA0 = &lds_a[s0 << 7];
  bf16x8* ldsB0 = &lds_b[s0 << 7];
  const int lane8 = lane << 3;

  for (int ky = 0; ky < 3; ++ky) {
    for (int kx = 0; kx < 3; ++kx) {
      const int tap = ky * 3 + kx;
      #pragma unroll
      for (int hk = 0; hk < 2; ++hk) {
        // A: visT2 row-group (y, g=hk*8+s); kx shift = +kx*8 elems; lanes contiguous.
        const __hip_bfloat16* a0p = vb + ((size_t)(((y0 + ky) << 4) + (hk << 3) + s0) << 9) + (kx << 3) + lane8;
        const __hip_bfloat16* a1p = vb + ((size_t)(((y0 + 1 + ky) << 4) + (hk << 3) + s0) << 9) + (kx << 3) + lane8;
        const __hip_bfloat16* bp  = Bt2 + (((size_t)(((tap << 1) + hk) << 3) + s0) << 10) + lane8;
        gl_lds16(a0p,        ldsA0);         // sub s0, m 0..63   (row0)
        gl_lds16(a1p,        ldsA0 + 64);    // sub s0, m 64..127 (row1)
        gl_lds16(a0p + 512,  ldsA0 + 128);   // sub s0+1, row0
        gl_lds16(a1p + 512,  ldsA0 + 192);   // sub s0+1, row1
        gl_lds16(bp,         ldsB0);         // sub s0, n 0..63
        gl_lds16(bp + 512,   ldsB0 + 64);    // sub s0, n 64..127
        gl_lds16(bp + 1024,  ldsB0 + 128);   // sub s0+1, n 0..63
        gl_lds16(bp + 1536,  ldsB0 + 192);   // sub s0+1, n 64..127
        __syncthreads();
        const bf16x8 b00 = lds_b[(quad << 7) + (wave << 5) + l15];
        const bf16x8 b01 = lds_b[(quad << 7) + (wave << 5) + 16 + l15];
        const bf16x8 b10 = lds_b[((4 + quad) << 7) + (wave << 5) + l15];
        const bf16x8 b11 = lds_b[((4 + quad) << 7) + (wave << 5) + 16 + l15];
        #pragma unroll
        for (int mt = 0; mt < 8; ++mt) {
          const bf16x8 a0 = lds_a[(quad << 7) + (mt << 4) + l15];
          const bf16x8 a1 = lds_a[((4 + quad) << 7) + (mt << 4) + l15];
          acc[mt][0] = __builtin_amdgcn_mfma_f32_16x16x32_bf16(a0, b00, acc[mt][0], 0, 0, 0);
          acc[mt][1] = __builtin_amdgcn_mfma_f32_16x16x32_bf16(a0, b01, acc[mt][1], 0, 0, 0);
          acc[mt][0] = __builtin_amdgcn_mfma_f32_16x16x32_bf16(a1, b10, acc[mt][0], 0, 0, 0);
          acc[mt][1] = __builtin_amdgcn_mfma_f32_16x16x32_bf16(a1, b11, acc[mt][1], 0, 0, 0);
        }
        __syncthreads();
      }
    }
  }

  // epilogue: bias + leaky + pool-max. C layout: n = nbase + l15, m = mt*16 + quad*4 + r.
  const float cb0 = conv_b[(wave << 5) + l15];
  const float cb1 = conv_b[(wave << 5) + 16 + l15];
  float pmax[2][2][2];
  #pragma unroll
  for (int i = 0; i < 8; ++i) (&pmax[0][0][0])[i] = -FLT_MAX;

  #pragma unroll
  for (int mt = 0; mt < 8; ++mt) {
    const int py = (y0 + (mt >> 2)) >= 31 ? 1 : 0;
    #pragma unroll
    for (int r = 0; r < 4; ++r) {
      const int x = ((mt & 3) << 4) + (quad << 2) + r;
      if (x < 62) {
        const int px = x >= 31 ? 1 : 0;
        float v0 = acc[mt][0][r] + cb0;  v0 = v0 >= 0.f ? v0 : 0.2f * v0;
        float v1 = acc[mt][1][r] + cb1;  v1 = v1 >= 0.f ? v1 : 0.2f * v1;
        pmax[0][py][px] = fmaxf(pmax[0][py][px], v0);
        pmax[1][py][px] = fmaxf(pmax[1][py][px], v1);
      }
    }
  }
  #pragma unroll
  for (int nt = 0; nt < 2; ++nt)
    #pragma unroll
    for (int py = 0; py < 2; ++py)
      #pragma unroll
      for (int px = 0; px < 2; ++px) {
        float v = pmax[nt][py][px];
        v = fmaxf(v, __shfl_xor(v, 16, 64));
        v = fmaxf(v, __shfl_xor(v, 32, 64));
        if (quad == 0) {
          const int n = (wave << 5) + (nt << 4) + l15;
          atomicMaxF(&pooled_v[(size_t)b * 512 + n * 4 + py * 2 + px], v);
        }
      }
}

// ---------------- fused scan (blocks 0..78) + xw (79..391) ----------------
// scan: per-256-chunk local scan + atomic chunk base (bucket ranges need disjointness, not order).
// xw:   xws = dis[n] * (topo @ gcn_w), bf16; dis recomputed from cnt (no scan dependency).
__global__ __launch_bounds__(256) void k_scan_xw(const int* __restrict__ cnt, int* __restrict__ offset,
                                                 int* __restrict__ total, float* __restrict__ dis,
                                                 const float* __restrict__ topo, const float* __restrict__ gcn_w,
                                                 __bf16* __restrict__ xws) {
  __shared__ f32x4 w4[4096];             // 64 KB: xw weights [d(128)][jq(32)]; scan reuses as int scratch
  __shared__ int sbase;
  const int tid = threadIdx.x;
  if (blockIdx.x < 79) {
    int* red = (int*)w4;
    const int n = blockIdx.x * 256 + tid;
    const int v = (n < NNODE) ? cnt[n] : 0;
    red[tid] = v; __syncthreads();
    for (int d = 1; d < 256; d <<= 1) {
      const int t = (tid >= d) ? red[tid - d] : 0;
      __syncthreads();
      red[tid] += t;
      __syncthreads();
    }
    if (tid == 255) sbase = atomicAdd(total, red[255]);
    __syncthreads();
    if (n < NNODE) {
      offset[n] = sbase + red[tid] - v;
      dis[n] = rsqrtf((float)(v + 1));
    }
  } else {
    const f32x4* gw4 = (const f32x4*)gcn_w;
    for (int i = tid; i < 4096; i += 256) w4[i] = gw4[i];
    __syncthreads();
    const int n0 = (blockIdx.x - 79) * 64;
    const int jq = tid & 31, ns = tid >> 5;          // 8 nodes per pass
    for (int pass = 0; pass < 8; ++pass) {
      const int n = n0 + pass * 8 + ns;
      if (n >= NNODE) break;
      const f32x4* tr4 = (const f32x4*)(topo + (size_t)n * 128);
      f32x4 a = {0.f, 0.f, 0.f, 0.f};
      for (int d4 = 0; d4 < 32; ++d4) {
        const f32x4 t = tr4[d4];
        const int base = (d4 << 7) + jq;             // (d4*4)*32 + jq
        #pragma unroll
        for (int m = 0; m < 4; ++m) {
          const f32x4 w = w4[base + m * 32];
          #pragma unroll
          for (int k = 0; k < 4; ++k) a[k] += t[m] * w[k];
        }
      }
      const float dn = rsqrtf((float)(cnt[n] + 1));
      bf16x4 o;
      #pragma unroll
      for (int k = 0; k < 4; ++k) o[k] = (__bf16)(a[k] * dn);
      ((bf16x4*)xws)[(size_t)n * 32 + jq] = o;
    }
  }
}

__global__ void k_bucket(const int* __restrict__ src, const int* __restrict__ dst,
                         const int* __restrict__ offset, int* __restrict__ fill,
                         int* __restrict__ sorted_src) {
  const int e = blockIdx.x * 256 + threadIdx.x;
  if (e >= NEDGE) return;
  const int t = dst[e];
  const int pos = atomicAdd(&fill[t], 1);
  sorted_src[offset[t] + pos] = src[e];
}

// ---------------- GCN gather: wave-per-node, bf16 rows, shfl reduce (no LDS/barriers) ----------------
// h[n] = leaky(b + dn*(xws[n] + sum_e xws[src_e]))   [xws pre-scaled by dis]
__global__ __launch_bounds__(256) void k_gather(const int* __restrict__ sorted_src,
                                                const int* __restrict__ offset, const int* __restrict__ cnt,
                                                const float* __restrict__ dis, const __bf16* __restrict__ xws,
                                                const float* __restrict__ gcn_b, __bf16* __restrict__ h) {
  const int wave = threadIdx.x >> 6, lane = threadIdx.x & 63;
  const int n = blockIdx.x * 4 + wave;               // grid 5000 -> n < 20000
  const int slot = lane >> 4, l16 = lane & 15;       // 4 edge slots x 16 dim-groups
  const int e0 = offset[n], ne = cnt[n];
  const bf16x8* x8 = (const bf16x8*)xws;             // row stride 16 (128 dims / 8)
  float a[8];
  if (slot == 0) {
    const bf16x8 v = x8[(size_t)n * 16 + l16];       // self term == xws[n] exactly
    #pragma unroll
    for (int k = 0; k < 8; ++k) a[k] = (float)v[k];
  } else {
    #pragma unroll
    for (int k = 0; k < 8; ++k) a[k] = 0.f;
  }
  for (int e = slot; e < ne; e += 4) {
    const int s = sorted_src[e0 + e];
    const bf16x8 v = x8[(size_t)s * 16 + l16];
    #pragma unroll
    for (int k = 0; k < 8; ++k) a[k] += (float)v[k];
  }
  #pragma unroll
  for (int k = 0; k < 8; ++k) {
    a[k] += __shfl_xor(a[k], 16, 64);
    a[k] += __shfl_xor(a[k], 32, 64);
  }
  if (slot == 0) {
    const float dn = dis[n];
    bf16x8 o;
    #pragma unroll
    for (int k = 0; k < 8; ++k) {
      float t = gcn_b[(l16 << 3) + k] + dn * a[k];
      t = t >= 0.f ? t : 0.2f * t;
      o[k] = (__bf16)t;
    }
    ((bf16x8*)h)[(size_t)n * 16 + l16] = o;
  }
}

__global__ void k_pool_t(const __bf16* __restrict__ h, const int* __restrict__ batch,
                         float* __restrict__ pooled_t) {
  const int d = threadIdx.x;           // 128
  const int n0 = blockIdx.x * 32;
  float run = -FLT_MAX;
  int cur = batch[n0];
  for (int i = 0; i < 32; ++i) {
    const int n = n0 + i;
    const int g = batch[n];
    if (g != cur) {
      atomicMaxF(&pooled_t[cur * 128 + d], run);
      run = -FLT_MAX; cur = g;
    }
    run = fmaxf(run, (float)h[(size_t)n * 128 + d]);
  }
  atomicMaxF(&pooled_t[cur * 128 + d], run);
}

// ---------------- merged FC epilogue: blocks 0..63 vision, 64..127 topo ----------------
__global__ __launch_bounds__(256) void k_fc(const float* __restrict__ pooled_v, const float* __restrict__ fcv_w,
                                            const float* __restrict__ fcv_b,
                                            const float* __restrict__ pooled_t, const float* __restrict__ fct_w,
                                            const float* __restrict__ fct_b,
                                            const float* __restrict__ inv_sigma, float* __restrict__ out) {
  const int tid = threadIdx.x;
  if (blockIdx.x < 64) {
    __shared__ f32x4 xr[128];
    const int b = blockIdx.x;
    if (tid < 128) xr[tid] = ((const f32x4*)pooled_v)[b * 128 + tid];
    __syncthreads();
    const f32x4* wr = (const f32x4*)(fcv_w + (size_t)tid * 512);
    f32x4 a4 = {0.f, 0.f, 0.f, 0.f};
    for (int f = 0; f < 128; ++f) {
      const f32x4 x = xr[f];
      const f32x4 w = wr[f];
      #pragma unroll
      for (int k = 0; k < 4; ++k) a4[k] += x[k] * w[k];
    }
    const float a = a4[0] + a4[1] + a4[2] + a4[3];
    out[b * 256 + tid] = a * inv_sigma[1] + fcv_b[tid];
  } else {
    __shared__ f32x4 xr2[32];
    const int b = blockIdx.x - 64;
    if (tid < 32) xr2[tid] = ((const f32x4*)pooled_t)[b * 32 + tid];
    __syncthreads();
    const f32x4* wr = (const f32x4*)(fct_w + (size_t)tid * 128);
    f32x4 a4 = {0.f, 0.f, 0.f, 0.f};
    for (int f = 0; f < 32; ++f) {
      const f32x4 x = xr2[f];
      const f32x4 w = wr[f];
      #pragma unroll
      for (int k = 0; k < 4; ++k) a4[k] += x[k] * w[k];
    }
    const float a = a4[0] + a4[1] + a4[2] + a4[3];
    out[NB * 256 + b * 256 + tid] = a * inv_sigma[2] + fct_b[tid];
  }
}

extern "C" void kernel_launch(void* const* d_in, const int* in_sizes, int n_in,
                              void* d_out, int out_size, void* d_ws, size_t ws_size,
                              hipStream_t stream) {
  const float* vis    = (const float*)d_in[0];
  const float* topo   = (const float*)d_in[1];
  const int*   eidx   = (const int*)d_in[2];
  const int*   batch  = (const int*)d_in[3];
  const float* conv_w = (const float*)d_in[4];
  const float* conv_b = (const float*)d_in[5];
  const float* conv_u = (const float*)d_in[6];
  const float* fcv_w  = (const float*)d_in[7];
  const float* fcv_b  = (const float*)d_in[8];
  const float* fcv_u  = (const float*)d_in[9];
  const float* gcn_w  = (const float*)d_in[10];
  const float* gcn_b  = (const float*)d_in[11];
  const float* fct_w  = (const float*)d_in[12];
  const float* fct_b  = (const float*)d_in[13];
  const float* fct_u  = (const float*)d_in[14];
  float* out = (float*)d_out;

  char* p = (char*)d_ws;
  float* inv_sigma  = (float*)p; p += 256;
  float* sn_scratch = (float*)p; p += 1796 * 4 + 240;           // v0,v1,v2,ss (pad to 16B)
  float* pooled_v   = (float*)p; p += (size_t)NB * 512 * 4;     // 131072
  float* pooled_t   = (float*)p; p += (size_t)NB * 128 * 4;     // 32768
  int*   cnt        = (int*)p;   p += (size_t)NNODE * 4;
  int*   offset     = (int*)p;   p += (size_t)NNODE * 4;
  int*   fill       = (int*)p;   p += (size_t)NNODE * 4;
  float* dis        = (float*)p; p += (size_t)NNODE * 4;
  int*   ntotal     = (int*)p;   p += 256;
  int*   sorted_src = (int*)p;   p += (size_t)NEDGE * 4;
  __bf16* xws       = (__bf16*)p; p += (size_t)NNODE * 128 * 2 + 256;
  __bf16* h         = (__bf16*)p; p += (size_t)NNODE * 128 * 2 + 256;
  __hip_bfloat16* Bt2 = (__hip_bfloat16*)p; p += (size_t)147456 * 2;
  p = (char*)(((uintptr_t)p + 255) & ~(uintptr_t)255);
  __hip_bfloat16* visT2 = (__hip_bfloat16*)p;                   // 64 MB + tail pad (OOB-read slack)

  // init + spectral norm (parallel 3-stage)
  hipLaunchKernelGGL(k_init,    dim3(128),  dim3(256), 0, stream, pooled_v, pooled_t, cnt, fill, sn_scratch, ntotal);
  hipLaunchKernelGGL(k_sn_v,    dim3(80),   dim3(256), 0, stream, conv_w, conv_u, fcv_w, fcv_u, fct_w, fct_u, sn_scratch);
  hipLaunchKernelGGL(k_sn_w,    dim3(160),  dim3(256), 0, stream, conv_w, fcv_w, fct_w, sn_scratch);
  hipLaunchKernelGGL(k_sn_fin,  dim3(1),    dim3(256), 0, stream, sn_scratch, inv_sigma);
  // fused prep: transpose + pack + deg
  hipLaunchKernelGGL(k_prep,    dim3(7172), dim3(256), 0, stream, vis, visT2, conv_w, inv_sigma, Bt2, eidx + NEDGE, cnt);
  // vision head main
  hipLaunchKernelGGL(k_conv,    dim3(64*31), dim3(256), 0, stream, visT2, Bt2, conv_b, pooled_v);
  // topo head: scan+xw fused, then bucket, gather, pool
  hipLaunchKernelGGL(k_scan_xw, dim3(392),  dim3(256), 0, stream, cnt, offset, ntotal, dis, topo, gcn_w, xws);
  hipLaunchKernelGGL(k_bucket,  dim3(2500), dim3(256), 0, stream, eidx, eidx + NEDGE, offset, fill, sorted_src);
  hipLaunchKernelGGL(k_gather,  dim3(5000), dim3(256), 0, stream, sorted_src, offset, cnt, dis, xws, gcn_b, h);
  hipLaunchKernelGGL(k_pool_t,  dim3(625),  dim3(128), 0, stream, h, batch, pooled_t);
  // merged FC epilogue (needs pooled_v + pooled_t)
  hipLaunchKernelGGL(k_fc,      dim3(128),  dim3(256), 0, stream, pooled_v, fcv_w, fcv_b, pooled_t, fct_w, fct_b, inv_sigma, out);
}

// Round 7
// 487.220 us; speedup vs baseline: 1.3288x; 1.0037x over previous
//
#include <hip/hip_runtime.h>
#include <hip/hip_bf16.h>
#include <float.h>
#include <stdint.h>

// Problem constants
#define NB   64      // batch / num graphs
#define CD   128     // channels / dims
#define OUTD 256
#define NNODE 20000
#define NEDGE 640000

typedef __bf16 bf16x8 __attribute__((ext_vector_type(8)));
typedef __bf16 bf16x4 __attribute__((ext_vector_type(4)));
typedef float  f32x4  __attribute__((ext_vector_type(4)));

__device__ inline void gl_lds16(const void* g, void* l) {
  __builtin_amdgcn_global_load_lds(
      (const __attribute__((address_space(1))) void*)g,
      (__attribute__((address_space(3))) void*)l, 16, 0, 0);
}

// float atomic max via signed/unsigned int monotonic trick (works for mixed signs)
__device__ inline void atomicMaxF(float* addr, float val) {
  if (val >= 0.f) atomicMax((int*)addr, __float_as_int(val));
  else            atomicMin((unsigned int*)addr, __float_as_uint(val));
}

// ---------------- init: pooled buffers (-FLT_MAX), CSR counters (=0), SN scratch (=0) ----------------
// sn_scratch layout: [0..1151]=v0, [1152..1663]=v1, [1664..1791]=v2, [1792..1795]=ss
__global__ void k_init(float* __restrict__ pooled_v, float* __restrict__ pooled_t,
                       int* __restrict__ cnt, int* __restrict__ fill,
                       float* __restrict__ sn_scratch, int* __restrict__ ntotal) {
  const int i = blockIdx.x * 256 + threadIdx.x;   // grid covers 32768
  if (i < NB * CD * 4) pooled_v[i] = -FLT_MAX;
  if (i < NB * CD)     pooled_t[i] = -FLT_MAX;
  if (i < NNODE)       { cnt[i] = 0; fill[i] = 0; }
  if (i < 1796)        sn_scratch[i] = 0.0f;
  if (i == 0)          *ntotal = 0;
}

// ---------------- SN stage 1: v = W^T u, 8-row chunks (80 blocks) ----------------
__global__ __launch_bounds__(256) void k_sn_v(const float* __restrict__ conv_w, const float* __restrict__ conv_u,
                                              const float* __restrict__ fcv_w,  const float* __restrict__ fcv_u,
                                              const float* __restrict__ fct_w,  const float* __restrict__ fct_u,
                                              float* __restrict__ sn) {
  const int bb = blockIdx.x;       // 0..79
  const float* W; const float* u; float* v; int C; int r0;
  if (bb < 16)      { W = conv_w; u = conv_u; v = sn;        C = 1152; r0 = bb * 8; }
  else if (bb < 48) { W = fcv_w;  u = fcv_u;  v = sn + 1152; C = 512;  r0 = (bb - 16) * 8; }
  else              { W = fct_w;  u = fct_u;  v = sn + 1664; C = 128;  r0 = (bb - 48) * 8; }
  const int tid = threadIdx.x;
  float acc[5] = {0.f, 0.f, 0.f, 0.f, 0.f};
  for (int i = r0; i < r0 + 8; ++i) {
    const float ui = u[i];
    const float* row = W + (size_t)i * C;
    #pragma unroll
    for (int t = 0; t < 5; ++t) {
      const int j = tid + t * 256;
      if (j < C) acc[t] += ui * row[j];
    }
  }
  #pragma unroll
  for (int t = 0; t < 5; ++t) {
    const int j = tid + t * 256;
    if (j < C) atomicAdd(&v[j], acc[t]);
  }
}

// ---------------- SN stage 2: ss[m] = ||W v||^2, one wave per row ----------------
__global__ __launch_bounds__(256) void k_sn_w(const float* __restrict__ conv_w,
                                              const float* __restrict__ fcv_w,
                                              const float* __restrict__ fct_w,
                                              float* __restrict__ sn) {
  const int gw = blockIdx.x * 4 + (threadIdx.x >> 6);   // global wave id, 0..639
  const int lane = threadIdx.x & 63;
  const float* W; const float* v; int C, m, row;
  if (gw < 128)      { W = conv_w; v = sn;        C = 1152; m = 0; row = gw; }
  else if (gw < 384) { W = fcv_w;  v = sn + 1152; C = 512;  m = 1; row = gw - 128; }
  else               { W = fct_w;  v = sn + 1664; C = 128;  m = 2; row = gw - 384; }
  const float* wr = W + (size_t)row * C;
  float y = 0.f;
  for (int c = lane; c < C; c += 64) y += wr[c] * v[c];
  #pragma unroll
  for (int s = 32; s > 0; s >>= 1) y += __shfl_xor(y, s, 64);
  if (lane == 0) atomicAdd(&sn[1792 + m], y * y);
}

// ---------------- SN stage 3: inv_sigma[m] = (||v||+eps)/||Wv|| ----------------
__global__ __launch_bounds__(256) void k_sn_fin(const float* __restrict__ sn, float* __restrict__ inv_sigma) {
  __shared__ float red[256];
  const int tid = threadIdx.x;
  const int off[4] = {0, 1152, 1664, 1792};
  for (int m = 0; m < 3; ++m) {
    const int C = off[m + 1] - off[m];
    float ss = 0.f;
    for (int j = tid; j < C; j += 256) { const float a = sn[off[m] + j]; ss += a * a; }
    red[tid] = ss; __syncthreads();
    for (int s = 128; s > 0; s >>= 1) { if (tid < s) red[tid] += red[tid + s]; __syncthreads(); }
    if (tid == 0) inv_sigma[m] = (sqrtf(red[0]) + 1e-12f) / sqrtf(sn[1792 + m]);
    __syncthreads();
  }
}

// ---------------- fused prep: transpose (blocks 0..4095) + pack (4096..4671) + deg (4672..7171) ----------------
__global__ __launch_bounds__(256) void k_prep(const float* __restrict__ vis, __hip_bfloat16* __restrict__ visT2,
                                              const float* __restrict__ conv_w, const float* __restrict__ inv_sigma,
                                              __hip_bfloat16* __restrict__ Bt2,
                                              const int* __restrict__ dst, int* __restrict__ cnt) {
  __shared__ float tile[8192];            // [c(128)][x(64)] (transpose branch only)
  const int bid = blockIdx.x;
  const int t = threadIdx.x;
  if (bid < 4096) {
    // NCHW f32 -> tiled bf16: visT2[b][y][g=c/8][x(64)][c8(8)]; f32x4 loads
    const int b = bid >> 6, y = bid & 63;
    const int c0 = t >> 4, x4 = (t & 15) << 2;
    const float* src = vis + (size_t)b * 524288 + y * 64;
    #pragma unroll
    for (int i = 0; i < 8; ++i) {
      const int c = i * 16 + c0;
      *(f32x4*)&tile[c * 64 + x4] = *(const f32x4*)(src + (size_t)c * 4096 + x4);
    }
    __syncthreads();
    bf16x8* dstv = (bf16x8*)(visT2 + ((size_t)bid << 13));   // bid*16*512 elems
    #pragma unroll
    for (int k = 0; k < 4; ++k) {
      const int j = k * 256 + t;            // chunk: g = j>>6, x = j&63
      const int g = j >> 6, x = j & 63;
      union { bf16x8 v; __hip_bfloat16 h[8]; } u;
      #pragma unroll
      for (int cc = 0; cc < 8; ++cc)
        u.h[cc] = __float2bfloat16(tile[(g * 8 + cc) * 64 + x]);
      dstv[j] = u.v;
    }
  } else if (bid < 4672) {
    // Bt2[tap(9)][halfk(2)][sub(8)][n(128)][c8(8)] = conv_w[n][ci=hk*64+s*8+j][tap] / sigma
    const int tt = (bid - 4096) * 256 + t;
    if (tt < 147456) {
      const int j = tt & 7, n = (tt >> 3) & 127, s = (tt >> 10) & 7, hk = (tt >> 13) & 1, tap = tt >> 14;
      const int ci = hk * 64 + s * 8 + j;
      Bt2[tt] = __float2bfloat16(conv_w[n * 1152 + ci * 9 + tap] * inv_sigma[0]);
    }
  } else {
    const int e = (bid - 4672) * 256 + t;
    if (e < NEDGE) atomicAdd(&cnt[dst[e]], 1);
  }
}

// ---------------- fused conv3x3 + bias + leaky + 31x31 maxpool (implicit GEMM, bf16 MFMA) ----------------
// R4 structure (proven ~92us full / ~47us per half). Split into 2 half-batch dispatches (b0=0,32)
// so the profiler's top-5 exposes the tail kernels (k_conv otherwise saturates the view).
__global__ __launch_bounds__(256, 4) void k_conv(const __hip_bfloat16* __restrict__ visT2,
                                                 const __hip_bfloat16* __restrict__ Bt2,
                                                 const float* __restrict__ conv_b,
                                                 float* __restrict__ pooled_v, int b0) {
  __shared__ bf16x8 lds_a[1024];   // 16 KB  [sub(8)][m(128)]
  __shared__ bf16x8 lds_b[1024];   // 16 KB  [sub(8)][n(128)]
  const int bx = blockIdx.x;
  const int b = b0 + bx / 31;
  const int y0 = (bx % 31) * 2;
  const int tid = threadIdx.x;
  const int wave = tid >> 6, lane = tid & 63;
  const int quad = lane >> 4, l15 = lane & 15;

  f32x4 acc[8][2];
  #pragma unroll
  for (int i = 0; i < 8; ++i) {
    acc[i][0] = f32x4{0.f, 0.f, 0.f, 0.f};
    acc[i][1] = f32x4{0.f, 0.f, 0.f, 0.f};
  }

  const __hip_bfloat16* vb = visT2 + ((size_t)b << 19);   // b*64*16*512
  const int s0 = wave << 1;                 // this wave stages subchunks s0, s0+1
  bf16x8* ldsA0 = &lds_a[s0 << 7];
  bf16x8* ldsB0 = &lds_b[s0 << 7];
  const int lane8 = lane << 3;

  for (int ky = 0; ky < 3; ++ky) {
    for (int kx = 0; kx < 3; ++kx) {
      const int tap = ky * 3 + kx;
      #pragma unroll
      for (int hk = 0; hk < 2; ++hk) {
        // A: visT2 row-group (y, g=hk*8+s); kx shift = +kx*8 elems; lanes contiguous.
        const __hip_bfloat16* a0p = vb + ((size_t)(((y0 + ky) << 4) + (hk << 3) + s0) << 9) + (kx << 3) + lane8;
        const __hip_bfloat16* a1p = vb + ((size_t)(((y0 + 1 + ky) << 4) + (hk << 3) + s0) << 9) + (kx << 3) + lane8;
        const __hip_bfloat16* bp  = Bt2 + (((size_t)(((tap << 1) + hk) << 3) + s0) << 10) + lane8;
        gl_lds16(a0p,        ldsA0);         // sub s0, m 0..63   (row0)
        gl_lds16(a1p,        ldsA0 + 64);    // sub s0, m 64..127 (row1)
        gl_lds16(a0p + 512,  ldsA0 + 128);   // sub s0+1, row0
        gl_lds16(a1p + 512,  ldsA0 + 192);   // sub s0+1, row1
        gl_lds16(bp,         ldsB0);         // sub s0, n 0..63
        gl_lds16(bp + 512,   ldsB0 + 64);    // sub s0, n 64..127
        gl_lds16(bp + 1024,  ldsB0 + 128);   // sub s0+1, n 0..63
        gl_lds16(bp + 1536,  ldsB0 + 192);   // sub s0+1, n 64..127
        __syncthreads();
        const bf16x8 b00 = lds_b[(quad << 7) + (wave << 5) + l15];
        const bf16x8 b01 = lds_b[(quad << 7) + (wave << 5) + 16 + l15];
        const bf16x8 b10 = lds_b[((4 + quad) << 7) + (wave << 5) + l15];
        const bf16x8 b11 = lds_b[((4 + quad) << 7) + (wave << 5) + 16 + l15];
        #pragma unroll
        for (int mt = 0; mt < 8; ++mt) {
          const bf16x8 a0 = lds_a[(quad << 7) + (mt << 4) + l15];
          const bf16x8 a1 = lds_a[((4 + quad) << 7) + (mt << 4) + l15];
          acc[mt][0] = __builtin_amdgcn_mfma_f32_16x16x32_bf16(a0, b00, acc[mt][0], 0, 0, 0);
          acc[mt][1] = __builtin_amdgcn_mfma_f32_16x16x32_bf16(a0, b01, acc[mt][1], 0, 0, 0);
          acc[mt][0] = __builtin_amdgcn_mfma_f32_16x16x32_bf16(a1, b10, acc[mt][0], 0, 0, 0);
          acc[mt][1] = __builtin_amdgcn_mfma_f32_16x16x32_bf16(a1, b11, acc[mt][1], 0, 0, 0);
        }
        __syncthreads();
      }
    }
  }

  // epilogue: bias + leaky + pool-max. C layout: n = nbase + l15, m = mt*16 + quad*4 + r.
  const float cb0 = conv_b[(wave << 5) + l15];
  const float cb1 = conv_b[(wave << 5) + 16 + l15];
  float pmax[2][2][2];
  #pragma unroll
  for (int i = 0; i < 8; ++i) (&pmax[0][0][0])[i] = -FLT_MAX;

  #pragma unroll
  for (int mt = 0; mt < 8; ++mt) {
    const int py = (y0 + (mt >> 2)) >= 31 ? 1 : 0;
    #pragma unroll
    for (int r = 0; r < 4; ++r) {
      const int x = ((mt & 3) << 4) + (quad << 2) + r;
      if (x < 62) {
        const int px = x >= 31 ? 1 : 0;
        float v0 = acc[mt][0][r] + cb0;  v0 = v0 >= 0.f ? v0 : 0.2f * v0;
        float v1 = acc[mt][1][r] + cb1;  v1 = v1 >= 0.f ? v1 : 0.2f * v1;
        pmax[0][py][px] = fmaxf(pmax[0][py][px], v0);
        pmax[1][py][px] = fmaxf(pmax[1][py][px], v1);
      }
    }
  }
  #pragma unroll
  for (int nt = 0; nt < 2; ++nt)
    #pragma unroll
    for (int py = 0; py < 2; ++py)
      #pragma unroll
      for (int px = 0; px < 2; ++px) {
        float v = pmax[nt][py][px];
        v = fmaxf(v, __shfl_xor(v, 16, 64));
        v = fmaxf(v, __shfl_xor(v, 32, 64));
        if (quad == 0) {
          const int n = (wave << 5) + (nt << 4) + l15;
          atomicMaxF(&pooled_v[(size_t)b * 512 + n * 4 + py * 2 + px], v);
        }
      }
}

// ---------------- fused scan (blocks 0..78) + xw (79..391) ----------------
__global__ __launch_bounds__(256) void k_scan_xw(const int* __restrict__ cnt, int* __restrict__ offset,
                                                 int* __restrict__ total, float* __restrict__ dis,
                                                 const float* __restrict__ topo, const float* __restrict__ gcn_w,
                                                 __bf16* __restrict__ xws) {
  __shared__ f32x4 w4[4096];             // 64 KB: xw weights [d(128)][jq(32)]; scan reuses as int scratch
  __shared__ int sbase;
  const int tid = threadIdx.x;
  if (blockIdx.x < 79) {
    int* red = (int*)w4;
    const int n = blockIdx.x * 256 + tid;
    const int v = (n < NNODE) ? cnt[n] : 0;
    red[tid] = v; __syncthreads();
    for (int d = 1; d < 256; d <<= 1) {
      const int t = (tid >= d) ? red[tid - d] : 0;
      __syncthreads();
      red[tid] += t;
      __syncthreads();
    }
    if (tid == 255) sbase = atomicAdd(total, red[255]);
    __syncthreads();
    if (n < NNODE) {
      offset[n] = sbase + red[tid] - v;
      dis[n] = rsqrtf((float)(v + 1));
    }
  } else {
    const f32x4* gw4 = (const f32x4*)gcn_w;
    for (int i = tid; i < 4096; i += 256) w4[i] = gw4[i];
    __syncthreads();
    const int n0 = (blockIdx.x - 79) * 64;
    const int jq = tid & 31, ns = tid >> 5;          // 8 nodes per pass
    for (int pass = 0; pass < 8; ++pass) {
      const int n = n0 + pass * 8 + ns;
      if (n >= NNODE) break;
      const f32x4* tr4 = (const f32x4*)(topo + (size_t)n * 128);
      f32x4 a = {0.f, 0.f, 0.f, 0.f};
      for (int d4 = 0; d4 < 32; ++d4) {
        const f32x4 t = tr4[d4];
        const int base = (d4 << 7) + jq;             // (d4*4)*32 + jq
        #pragma unroll
        for (int m = 0; m < 4; ++m) {
          const f32x4 w = w4[base + m * 32];
          #pragma unroll
          for (int k = 0; k < 4; ++k) a[k] += t[m] * w[k];
        }
      }
      const float dn = rsqrtf((float)(cnt[n] + 1));
      bf16x4 o;
      #pragma unroll
      for (int k = 0; k < 4; ++k) o[k] = (__bf16)(a[k] * dn);
      ((bf16x4*)xws)[(size_t)n * 32 + jq] = o;
    }
  }
}

__global__ void k_bucket(const int* __restrict__ src, const int* __restrict__ dst,
                         const int* __restrict__ offset, int* __restrict__ fill,
                         int* __restrict__ sorted_src) {
  const int e = blockIdx.x * 256 + threadIdx.x;
  if (e >= NEDGE) return;
  const int t = dst[e];
  const int pos = atomicAdd(&fill[t], 1);
  sorted_src[offset[t] + pos] = src[e];
}

// ---------------- GCN gather + fused global-max-pool (k_pool_t eliminated) ----------------
// h[n] = leaky(b + dn*(xws[n] + sum_e xws[src_e]))   [xws pre-scaled by dis]
// Block handles nodes 4b..4b+3 (one per wave); h rows staged in LDS, per-graph max reduced
// in-block (sorted batch -> all-same-graph common case: 128 atomics/block instead of 512).
__global__ __launch_bounds__(256) void k_gather(const int* __restrict__ sorted_src,
                                                const int* __restrict__ offset, const int* __restrict__ cnt,
                                                const float* __restrict__ dis, const __bf16* __restrict__ xws,
                                                const float* __restrict__ gcn_b, const int* __restrict__ batch,
                                                float* __restrict__ pooled_t) {
  __shared__ float hred[4][128];
  __shared__ int hg[4];
  const int wave = threadIdx.x >> 6, lane = threadIdx.x & 63;
  const int n = blockIdx.x * 4 + wave;               // grid 5000 -> n < 20000
  const int slot = lane >> 4, l16 = lane & 15;       // 4 edge slots x 16 dim-groups
  const int e0 = offset[n], ne = cnt[n];
  const bf16x8* x8 = (const bf16x8*)xws;             // row stride 16 (128 dims / 8)
  float a[8];
  if (slot == 0) {
    const bf16x8 v = x8[(size_t)n * 16 + l16];       // self term == xws[n] exactly
    #pragma unroll
    for (int k = 0; k < 8; ++k) a[k] = (float)v[k];
  } else {
    #pragma unroll
    for (int k = 0; k < 8; ++k) a[k] = 0.f;
  }
  for (int e = slot; e < ne; e += 4) {
    const int s = sorted_src[e0 + e];
    const bf16x8 v = x8[(size_t)s * 16 + l16];
    #pragma unroll
    for (int k = 0; k < 8; ++k) a[k] += (float)v[k];
  }
  #pragma unroll
  for (int k = 0; k < 8; ++k) {
    a[k] += __shfl_xor(a[k], 16, 64);
    a[k] += __shfl_xor(a[k], 32, 64);
  }
  if (lane == 0) hg[wave] = batch[n];
  if (slot == 0) {
    const float dn = dis[n];
    #pragma unroll
    for (int k = 0; k < 8; ++k) {
      float t = gcn_b[(l16 << 3) + k] + dn * a[k];
      hred[wave][(l16 << 3) + k] = t >= 0.f ? t : 0.2f * t;
    }
  }
  __syncthreads();
  const int tid = threadIdx.x;
  if (tid < 128) {
    const int g0 = hg[0], g1 = hg[1], g2 = hg[2], g3 = hg[3];
    if (g0 == g1 && g1 == g2 && g2 == g3) {          // common case (sorted batch, ~312-node runs)
      const float m = fmaxf(fmaxf(hred[0][tid], hred[1][tid]), fmaxf(hred[2][tid], hred[3][tid]));
      atomicMaxF(&pooled_t[g0 * 128 + tid], m);
    } else {
      atomicMaxF(&pooled_t[g0 * 128 + tid], hred[0][tid]);
      atomicMaxF(&pooled_t[g1 * 128 + tid], hred[1][tid]);
      atomicMaxF(&pooled_t[g2 * 128 + tid], hred[2][tid]);
      atomicMaxF(&pooled_t[g3 * 128 + tid], hred[3][tid]);
    }
  }
}

// ---------------- merged FC epilogue: blocks 0..63 vision, 64..127 topo ----------------
__global__ __launch_bounds__(256) void k_fc(const float* __restrict__ pooled_v, const float* __restrict__ fcv_w,
                                            const float* __restrict__ fcv_b,
                                            const float* __restrict__ pooled_t, const float* __restrict__ fct_w,
                                            const float* __restrict__ fct_b,
                                            const float* __restrict__ inv_sigma, float* __restrict__ out) {
  const int tid = threadIdx.x;
  if (blockIdx.x < 64) {
    __shared__ f32x4 xr[128];
    const int b = blockIdx.x;
    if (tid < 128) xr[tid] = ((const f32x4*)pooled_v)[b * 128 + tid];
    __syncthreads();
    const f32x4* wr = (const f32x4*)(fcv_w + (size_t)tid * 512);
    f32x4 a4 = {0.f, 0.f, 0.f, 0.f};
    for (int f = 0; f < 128; ++f) {
      const f32x4 x = xr[f];
      const f32x4 w = wr[f];
      #pragma unroll
      for (int k = 0; k < 4; ++k) a4[k] += x[k] * w[k];
    }
    const float a = a4[0] + a4[1] + a4[2] + a4[3];
    out[b * 256 + tid] = a * inv_sigma[1] + fcv_b[tid];
  } else {
    __shared__ f32x4 xr2[32];
    const int b = blockIdx.x - 64;
    if (tid < 32) xr2[tid] = ((const f32x4*)pooled_t)[b * 32 + tid];
    __syncthreads();
    const f32x4* wr = (const f32x4*)(fct_w + (size_t)tid * 128);
    f32x4 a4 = {0.f, 0.f, 0.f, 0.f};
    for (int f = 0; f < 32; ++f) {
      const f32x4 x = xr2[f];
      const f32x4 w = wr[f];
      #pragma unroll
      for (int k = 0; k < 4; ++k) a4[k] += x[k] * w[k];
    }
    const float a = a4[0] + a4[1] + a4[2] + a4[3];
    out[NB * 256 + b * 256 + tid] = a * inv_sigma[2] + fct_b[tid];
  }
}

extern "C" void kernel_launch(void* const* d_in, const int* in_sizes, int n_in,
                              void* d_out, int out_size, void* d_ws, size_t ws_size,
                              hipStream_t stream) {
  const float* vis    = (const float*)d_in[0];
  const float* topo   = (const float*)d_in[1];
  const int*   eidx   = (const int*)d_in[2];
  const int*   batch  = (const int*)d_in[3];
  const float* conv_w = (const float*)d_in[4];
  const float* conv_b = (const float*)d_in[5];
  const float* conv_u = (const float*)d_in[6];
  const float* fcv_w  = (const float*)d_in[7];
  const float* fcv_b  = (const float*)d_in[8];
  const float* fcv_u  = (const float*)d_in[9];
  const float* gcn_w  = (const float*)d_in[10];
  const float* gcn_b  = (const float*)d_in[11];
  const float* fct_w  = (const float*)d_in[12];
  const float* fct_b  = (const float*)d_in[13];
  const float* fct_u  = (const float*)d_in[14];
  float* out = (float*)d_out;

  char* p = (char*)d_ws;
  float* inv_sigma  = (float*)p; p += 256;
  float* sn_scratch = (float*)p; p += 1796 * 4 + 240;           // v0,v1,v2,ss (pad to 16B)
  float* pooled_v   = (float*)p; p += (size_t)NB * 512 * 4;     // 131072
  float* pooled_t   = (float*)p; p += (size_t)NB * 128 * 4;     // 32768
  int*   cnt        = (int*)p;   p += (size_t)NNODE * 4;
  int*   offset     = (int*)p;   p += (size_t)NNODE * 4;
  int*   fill       = (int*)p;   p += (size_t)NNODE * 4;
  float* dis        = (float*)p; p += (size_t)NNODE * 4;
  int*   ntotal     = (int*)p;   p += 256;
  int*   sorted_src = (int*)p;   p += (size_t)NEDGE * 4;
  __bf16* xws       = (__bf16*)p; p += (size_t)NNODE * 128 * 2 + 256;
  __hip_bfloat16* Bt2 = (__hip_bfloat16*)p; p += (size_t)147456 * 2;
  p = (char*)(((uintptr_t)p + 255) & ~(uintptr_t)255);
  __hip_bfloat16* visT2 = (__hip_bfloat16*)p;                   // 64 MB + tail pad (OOB-read slack)

  // init + spectral norm (parallel 3-stage)
  hipLaunchKernelGGL(k_init,    dim3(128),  dim3(256), 0, stream, pooled_v, pooled_t, cnt, fill, sn_scratch, ntotal);
  hipLaunchKernelGGL(k_sn_v,    dim3(80),   dim3(256), 0, stream, conv_w, conv_u, fcv_w, fcv_u, fct_w, fct_u, sn_scratch);
  hipLaunchKernelGGL(k_sn_w,    dim3(160),  dim3(256), 0, stream, conv_w, fcv_w, fct_w, sn_scratch);
  hipLaunchKernelGGL(k_sn_fin,  dim3(1),    dim3(256), 0, stream, sn_scratch, inv_sigma);
  // fused prep: transpose + pack + deg
  hipLaunchKernelGGL(k_prep,    dim3(7172), dim3(256), 0, stream, vis, visT2, conv_w, inv_sigma, Bt2, eidx + NEDGE, cnt);
  // vision head main, split into two half-batch dispatches (profiler tail visibility)
  hipLaunchKernelGGL(k_conv,    dim3(32*31), dim3(256), 0, stream, visT2, Bt2, conv_b, pooled_v, 0);
  hipLaunchKernelGGL(k_conv,    dim3(32*31), dim3(256), 0, stream, visT2, Bt2, conv_b, pooled_v, 32);
  // topo head: scan+xw fused, bucket, gather (pool fused in)
  hipLaunchKernelGGL(k_scan_xw, dim3(392),  dim3(256), 0, stream, cnt, offset, ntotal, dis, topo, gcn_w, xws);
  hipLaunchKernelGGL(k_bucket,  dim3(2500), dim3(256), 0, stream, eidx, eidx + NEDGE, offset, fill, sorted_src);
  hipLaunchKernelGGL(k_gather,  dim3(5000), dim3(256), 0, stream, sorted_src, offset, cnt, dis, xws, gcn_b, batch, pooled_t);
  // merged FC epilogue (needs pooled_v + pooled_t)
  hipLaunchKernelGGL(k_fc,      dim3(128),  dim3(256), 0, stream, pooled_v, fcv_w, fcv_b, pooled_t, fct_w, fct_b, inv_sigma, out);
}

// Round 8
// 475.744 us; speedup vs baseline: 1.3609x; 1.0241x over previous
//
#include <hip/hip_runtime.h>
#include <hip/hip_bf16.h>
#include <float.h>
#include <stdint.h>

// Problem constants
#define NB   64      // batch / num graphs
#define CD   128     // channels / dims
#define OUTD 256
#define NNODE 20000
#define NEDGE 640000

typedef __bf16 bf16x8 __attribute__((ext_vector_type(8)));
typedef __bf16 bf16x4 __attribute__((ext_vector_type(4)));
typedef float  f32x4  __attribute__((ext_vector_type(4)));

__device__ inline void gl_lds16(const void* g, void* l) {
  __builtin_amdgcn_global_load_lds(
      (const __attribute__((address_space(1))) void*)g,
      (__attribute__((address_space(3))) void*)l, 16, 0, 0);
}

// float atomic max via signed/unsigned int monotonic trick (works for mixed signs)
__device__ inline void atomicMaxF(float* addr, float val) {
  if (val >= 0.f) atomicMax((int*)addr, __float_as_int(val));
  else            atomicMin((unsigned int*)addr, __float_as_uint(val));
}

// ---------------- init: pooled buffers (-FLT_MAX), CSR counters (=0), SN scratch (=0) ----------------
// sn_scratch layout: [0..1151]=v0, [1152..1663]=v1, [1664..1791]=v2, [1792..1795]=ss
__global__ void k_init(float* __restrict__ pooled_v, float* __restrict__ pooled_t,
                       int* __restrict__ cnt, int* __restrict__ fill,
                       float* __restrict__ sn_scratch, int* __restrict__ ntotal) {
  const int i = blockIdx.x * 256 + threadIdx.x;   // grid covers 32768
  if (i < NB * CD * 4) pooled_v[i] = -FLT_MAX;
  if (i < NB * CD)     pooled_t[i] = -FLT_MAX;
  if (i < NNODE)       { cnt[i] = 0; fill[i] = 0; }
  if (i < 1796)        sn_scratch[i] = 0.0f;
  if (i == 0)          *ntotal = 0;
}

// ---------------- SN stage 1: v = W^T u, 8-row chunks (80 blocks) ----------------
__global__ __launch_bounds__(256) void k_sn_v(const float* __restrict__ conv_w, const float* __restrict__ conv_u,
                                              const float* __restrict__ fcv_w,  const float* __restrict__ fcv_u,
                                              const float* __restrict__ fct_w,  const float* __restrict__ fct_u,
                                              float* __restrict__ sn) {
  const int bb = blockIdx.x;       // 0..79
  const float* W; const float* u; float* v; int C; int r0;
  if (bb < 16)      { W = conv_w; u = conv_u; v = sn;        C = 1152; r0 = bb * 8; }
  else if (bb < 48) { W = fcv_w;  u = fcv_u;  v = sn + 1152; C = 512;  r0 = (bb - 16) * 8; }
  else              { W = fct_w;  u = fct_u;  v = sn + 1664; C = 128;  r0 = (bb - 48) * 8; }
  const int tid = threadIdx.x;
  float acc[5] = {0.f, 0.f, 0.f, 0.f, 0.f};
  for (int i = r0; i < r0 + 8; ++i) {
    const float ui = u[i];
    const float* row = W + (size_t)i * C;
    #pragma unroll
    for (int t = 0; t < 5; ++t) {
      const int j = tid + t * 256;
      if (j < C) acc[t] += ui * row[j];
    }
  }
  #pragma unroll
  for (int t = 0; t < 5; ++t) {
    const int j = tid + t * 256;
    if (j < C) atomicAdd(&v[j], acc[t]);
  }
}

// ---------------- SN stage 2: ss[m] = ||W v||^2, one wave per row ----------------
__global__ __launch_bounds__(256) void k_sn_w(const float* __restrict__ conv_w,
                                              const float* __restrict__ fcv_w,
                                              const float* __restrict__ fct_w,
                                              float* __restrict__ sn) {
  const int gw = blockIdx.x * 4 + (threadIdx.x >> 6);   // global wave id, 0..639
  const int lane = threadIdx.x & 63;
  const float* W; const float* v; int C, m, row;
  if (gw < 128)      { W = conv_w; v = sn;        C = 1152; m = 0; row = gw; }
  else if (gw < 384) { W = fcv_w;  v = sn + 1152; C = 512;  m = 1; row = gw - 128; }
  else               { W = fct_w;  v = sn + 1664; C = 128;  m = 2; row = gw - 384; }
  const float* wr = W + (size_t)row * C;
  float y = 0.f;
  for (int c = lane; c < C; c += 64) y += wr[c] * v[c];
  #pragma unroll
  for (int s = 32; s > 0; s >>= 1) y += __shfl_xor(y, s, 64);
  if (lane == 0) atomicAdd(&sn[1792 + m], y * y);
}

// ---------------- SN stage 3: inv_sigma[m] = (||v||+eps)/||Wv|| ----------------
__global__ __launch_bounds__(256) void k_sn_fin(const float* __restrict__ sn, float* __restrict__ inv_sigma) {
  __shared__ float red[256];
  const int tid = threadIdx.x;
  const int off[4] = {0, 1152, 1664, 1792};
  for (int m = 0; m < 3; ++m) {
    const int C = off[m + 1] - off[m];
    float ss = 0.f;
    for (int j = tid; j < C; j += 256) { const float a = sn[off[m] + j]; ss += a * a; }
    red[tid] = ss; __syncthreads();
    for (int s = 128; s > 0; s >>= 1) { if (tid < s) red[tid] += red[tid + s]; __syncthreads(); }
    if (tid == 0) inv_sigma[m] = (sqrtf(red[0]) + 1e-12f) / sqrtf(sn[1792 + m]);
    __syncthreads();
  }
}

// ---------------- fused prep: transpose (blocks 0..1023) + pack (1024..1599) + deg (1600..4099) ----------------
// R9 transpose: block = (b, y-quad). Rows y..y+3 contiguous in NCHW -> each channel read is ONE
// fully-coalesced 1KB load (was 4 x 256B segments); 32 independent loads/wave for MLP. bf16 LDS 64KB.
__global__ __launch_bounds__(256, 2) void k_prep(const float* __restrict__ vis, __bf16* __restrict__ visT2,
                                                 const float* __restrict__ conv_w, const float* __restrict__ inv_sigma,
                                                 __hip_bfloat16* __restrict__ Bt2,
                                                 const int* __restrict__ dst, int* __restrict__ cnt) {
  __shared__ __bf16 tile[32768];          // [c(128)][f(256)=y'(4)*64+x(64)]  64 KB (transpose branch only)
  const int bid = blockIdx.x;
  const int t = threadIdx.x;
  if (bid < 1024) {
    const int b = bid >> 4, y0 = (bid & 15) << 2;
    const int wave = t >> 6, lane = t & 63;
    const float* src = vis + (size_t)b * 524288 + y0 * 64 + lane * 4;
    #pragma unroll
    for (int i = 0; i < 32; ++i) {
      const int c = wave * 32 + i;
      const f32x4 v = *(const f32x4*)(src + (size_t)c * 4096);
      bf16x4 o;
      #pragma unroll
      for (int k = 0; k < 4; ++k) o[k] = (__bf16)v[k];
      *(bf16x4*)&tile[c * 256 + lane * 4] = o;
    }
    __syncthreads();
    // write: visT2[b][y0+yy][g][x][c8], fully coalesced 16B/lane stores
    #pragma unroll
    for (int yy = 0; yy < 4; ++yy) {
      bf16x8* dstv = (bf16x8*)(visT2 + ((size_t)((b << 6) + y0 + yy) << 13));
      #pragma unroll
      for (int k = 0; k < 4; ++k) {
        const int j = k * 256 + t;          // g = j>>6, x = j&63
        const int g = j >> 6, x = j & 63;
        union { bf16x8 v; __bf16 h[8]; } u;
        #pragma unroll
        for (int cc = 0; cc < 8; ++cc)
          u.h[cc] = tile[(g * 8 + cc) * 256 + yy * 64 + x];
        dstv[j] = u.v;
      }
    }
  } else if (bid < 1600) {
    // Bt2[tap(9)][halfk(2)][sub(8)][n(128)][c8(8)] = conv_w[n][ci=hk*64+s*8+j][tap] / sigma
    const int tt = (bid - 1024) * 256 + t;
    if (tt < 147456) {
      const int j = tt & 7, n = (tt >> 3) & 127, s = (tt >> 10) & 7, hk = (tt >> 13) & 1, tap = tt >> 14;
      const int ci = hk * 64 + s * 8 + j;
      Bt2[tt] = __float2bfloat16(conv_w[n * 1152 + ci * 9 + tap] * inv_sigma[0]);
    }
  } else {
    const int e = (bid - 1600) * 256 + t;
    if (e < NEDGE) atomicAdd(&cnt[dst[e]], 1);
  }
}

// ---------------- fused conv3x3+bias+leaky+maxpool (blocks 0..1983) + bucket (1984..4483) ----------------
// Conv: proven R4 structure (~92us). Bucket blocks appended AFTER conv blocks: they slot into CUs
// as conv blocks retire, overlapping bucket's scattered traffic with conv's idle memory pipe (24% HBM).
__global__ __launch_bounds__(256, 4) void k_convb(const __hip_bfloat16* __restrict__ visT2,
                                                  const __hip_bfloat16* __restrict__ Bt2,
                                                  const float* __restrict__ conv_b,
                                                  float* __restrict__ pooled_v,
                                                  const int* __restrict__ srcE, const int* __restrict__ dstE,
                                                  const int* __restrict__ offset, int* __restrict__ fill,
                                                  int* __restrict__ sorted_src) {
  __shared__ bf16x8 lds_a[1024];   // 16 KB  [sub(8)][m(128)]
  __shared__ bf16x8 lds_b[1024];   // 16 KB  [sub(8)][n(128)]
  const int bid = blockIdx.x;
  if (bid >= 1984) {               // bucket branch (no LDS, no barriers)
    const int e = (bid - 1984) * 256 + threadIdx.x;
    if (e < NEDGE) {
      const int tt = dstE[e];
      const int pos = atomicAdd(&fill[tt], 1);
      sorted_src[offset[tt] + pos] = srcE[e];
    }
    return;
  }
  const int bx = bid;
  const int b = bx / 31;
  const int y0 = (bx % 31) * 2;
  const int tid = threadIdx.x;
  const int wave = tid >> 6, lane = tid & 63;
  const int quad = lane >> 4, l15 = lane & 15;

  f32x4 acc[8][2];
  #pragma unroll
  for (int i = 0; i < 8; ++i) {
    acc[i][0] = f32x4{0.f, 0.f, 0.f, 0.f};
    acc[i][1] = f32x4{0.f, 0.f, 0.f, 0.f};
  }

  const __hip_bfloat16* vb = visT2 + ((size_t)b << 19);   // b*64*16*512
  const int s0 = wave << 1;                 // this wave stages subchunks s0, s0+1
  bf16x8* ldsA0 = &lds_a[s0 << 7];
  bf16x8* ldsB0 = &lds_b[s0 << 7];
  const int lane8 = lane << 3;

  for (int ky = 0; ky < 3; ++ky) {
    for (int kx = 0; kx < 3; ++kx) {
      const int tap = ky * 3 + kx;
      #pragma unroll
      for (int hk = 0; hk < 2; ++hk) {
        // A: visT2 row-group (y, g=hk*8+s); kx shift = +kx*8 elems; lanes contiguous.
        const __hip_bfloat16* a0p = vb + ((size_t)(((y0 + ky) << 4) + (hk << 3) + s0) << 9) + (kx << 3) + lane8;
        const __hip_bfloat16* a1p = vb + ((size_t)(((y0 + 1 + ky) << 4) + (hk << 3) + s0) << 9) + (kx << 3) + lane8;
        const __hip_bfloat16* bp  = Bt2 + (((size_t)(((tap << 1) + hk) << 3) + s0) << 10) + lane8;
        gl_lds16(a0p,        ldsA0);         // sub s0, m 0..63   (row0)
        gl_lds16(a1p,        ldsA0 + 64);    // sub s0, m 64..127 (row1)
        gl_lds16(a0p + 512,  ldsA0 + 128);   // sub s0+1, row0
        gl_lds16(a1p + 512,  ldsA0 + 192);   // sub s0+1, row1
        gl_lds16(bp,         ldsB0);         // sub s0, n 0..63
        gl_lds16(bp + 512,   ldsB0 + 64);    // sub s0, n 64..127
        gl_lds16(bp + 1024,  ldsB0 + 128);   // sub s0+1, n 0..63
        gl_lds16(bp + 1536,  ldsB0 + 192);   // sub s0+1, n 64..127
        __syncthreads();
        const bf16x8 b00 = lds_b[(quad << 7) + (wave << 5) + l15];
        const bf16x8 b01 = lds_b[(quad << 7) + (wave << 5) + 16 + l15];
        const bf16x8 b10 = lds_b[((4 + quad) << 7) + (wave << 5) + l15];
        const bf16x8 b11 = lds_b[((4 + quad) << 7) + (wave << 5) + 16 + l15];
        #pragma unroll
        for (int mt = 0; mt < 8; ++mt) {
          const bf16x8 a0 = lds_a[(quad << 7) + (mt << 4) + l15];
          const bf16x8 a1 = lds_a[((4 + quad) << 7) + (mt << 4) + l15];
          acc[mt][0] = __builtin_amdgcn_mfma_f32_16x16x32_bf16(a0, b00, acc[mt][0], 0, 0, 0);
          acc[mt][1] = __builtin_amdgcn_mfma_f32_16x16x32_bf16(a0, b01, acc[mt][1], 0, 0, 0);
          acc[mt][0] = __builtin_amdgcn_mfma_f32_16x16x32_bf16(a1, b10, acc[mt][0], 0, 0, 0);
          acc[mt][1] = __builtin_amdgcn_mfma_f32_16x16x32_bf16(a1, b11, acc[mt][1], 0, 0, 0);
        }
        __syncthreads();
      }
    }
  }

  // epilogue: bias + leaky + pool-max. C layout: n = nbase + l15, m = mt*16 + quad*4 + r.
  const float cb0 = conv_b[(wave << 5) + l15];
  const float cb1 = conv_b[(wave << 5) + 16 + l15];
  float pmax[2][2][2];
  #pragma unroll
  for (int i = 0; i < 8; ++i) (&pmax[0][0][0])[i] = -FLT_MAX;

  #pragma unroll
  for (int mt = 0; mt < 8; ++mt) {
    const int py = (y0 + (mt >> 2)) >= 31 ? 1 : 0;
    #pragma unroll
    for (int r = 0; r < 4; ++r) {
      const int x = ((mt & 3) << 4) + (quad << 2) + r;
      if (x < 62) {
        const int px = x >= 31 ? 1 : 0;
        float v0 = acc[mt][0][r] + cb0;  v0 = v0 >= 0.f ? v0 : 0.2f * v0;
        float v1 = acc[mt][1][r] + cb1;  v1 = v1 >= 0.f ? v1 : 0.2f * v1;
        pmax[0][py][px] = fmaxf(pmax[0][py][px], v0);
        pmax[1][py][px] = fmaxf(pmax[1][py][px], v1);
      }
    }
  }
  #pragma unroll
  for (int nt = 0; nt < 2; ++nt)
    #pragma unroll
    for (int py = 0; py < 2; ++py)
      #pragma unroll
      for (int px = 0; px < 2; ++px) {
        float v = pmax[nt][py][px];
        v = fmaxf(v, __shfl_xor(v, 16, 64));
        v = fmaxf(v, __shfl_xor(v, 32, 64));
        if (quad == 0) {
          const int n = (wave << 5) + (nt << 4) + l15;
          atomicMaxF(&pooled_v[(size_t)b * 512 + n * 4 + py * 2 + px], v);
        }
      }
}

// ---------------- fused scan (blocks 0..78) + xw (79..391) ----------------
__global__ __launch_bounds__(256) void k_scan_xw(const int* __restrict__ cnt, int* __restrict__ offset,
                                                 int* __restrict__ total, float* __restrict__ dis,
                                                 const float* __restrict__ topo, const float* __restrict__ gcn_w,
                                                 __bf16* __restrict__ xws) {
  __shared__ f32x4 w4[4096];             // 64 KB: xw weights [d(128)][jq(32)]; scan reuses as int scratch
  __shared__ int sbase;
  const int tid = threadIdx.x;
  if (blockIdx.x < 79) {
    int* red = (int*)w4;
    const int n = blockIdx.x * 256 + tid;
    const int v = (n < NNODE) ? cnt[n] : 0;
    red[tid] = v; __syncthreads();
    for (int d = 1; d < 256; d <<= 1) {
      const int t = (tid >= d) ? red[tid - d] : 0;
      __syncthreads();
      red[tid] += t;
      __syncthreads();
    }
    if (tid == 255) sbase = atomicAdd(total, red[255]);
    __syncthreads();
    if (n < NNODE) {
      offset[n] = sbase + red[tid] - v;
      dis[n] = rsqrtf((float)(v + 1));
    }
  } else {
    const f32x4* gw4 = (const f32x4*)gcn_w;
    for (int i = tid; i < 4096; i += 256) w4[i] = gw4[i];
    __syncthreads();
    const int n0 = (blockIdx.x - 79) * 64;
    const int jq = tid & 31, ns = tid >> 5;          // 8 nodes per pass
    for (int pass = 0; pass < 8; ++pass) {
      const int n = n0 + pass * 8 + ns;
      if (n >= NNODE) break;
      const f32x4* tr4 = (const f32x4*)(topo + (size_t)n * 128);
      f32x4 a = {0.f, 0.f, 0.f, 0.f};
      for (int d4 = 0; d4 < 32; ++d4) {
        const f32x4 t = tr4[d4];
        const int base = (d4 << 7) + jq;             // (d4*4)*32 + jq
        #pragma unroll
        for (int m = 0; m < 4; ++m) {
          const f32x4 w = w4[base + m * 32];
          #pragma unroll
          for (int k = 0; k < 4; ++k) a[k] += t[m] * w[k];
        }
      }
      const float dn = rsqrtf((float)(cnt[n] + 1));
      bf16x4 o;
      #pragma unroll
      for (int k = 0; k < 4; ++k) o[k] = (__bf16)(a[k] * dn);
      ((bf16x4*)xws)[(size_t)n * 32 + jq] = o;
    }
  }
}

// ---------------- GCN gather + fused global-max-pool ----------------
// h[n] = leaky(b + dn*(xws[n] + sum_e xws[src_e]))   [xws pre-scaled by dis]
__global__ __launch_bounds__(256) void k_gather(const int* __restrict__ sorted_src,
                                                const int* __restrict__ offset, const int* __restrict__ cnt,
                                                const float* __restrict__ dis, const __bf16* __restrict__ xws,
                                                const float* __restrict__ gcn_b, const int* __restrict__ batch,
                                                float* __restrict__ pooled_t) {
  __shared__ float hred[4][128];
  __shared__ int hg[4];
  const int wave = threadIdx.x >> 6, lane = threadIdx.x & 63;
  const int n = blockIdx.x * 4 + wave;               // grid 5000 -> n < 20000
  const int slot = lane >> 4, l16 = lane & 15;       // 4 edge slots x 16 dim-groups
  const int e0 = offset[n], ne = cnt[n];
  const bf16x8* x8 = (const bf16x8*)xws;             // row stride 16 (128 dims / 8)
  float a[8];
  if (slot == 0) {
    const bf16x8 v = x8[(size_t)n * 16 + l16];       // self term == xws[n] exactly
    #pragma unroll
    for (int k = 0; k < 8; ++k) a[k] = (float)v[k];
  } else {
    #pragma unroll
    for (int k = 0; k < 8; ++k) a[k] = 0.f;
  }
  for (int e = slot; e < ne; e += 4) {
    const int s = sorted_src[e0 + e];
    const bf16x8 v = x8[(size_t)s * 16 + l16];
    #pragma unroll
    for (int k = 0; k < 8; ++k) a[k] += (float)v[k];
  }
  #pragma unroll
  for (int k = 0; k < 8; ++k) {
    a[k] += __shfl_xor(a[k], 16, 64);
    a[k] += __shfl_xor(a[k], 32, 64);
  }
  if (lane == 0) hg[wave] = batch[n];
  if (slot == 0) {
    const float dn = dis[n];
    #pragma unroll
    for (int k = 0; k < 8; ++k) {
      float t = gcn_b[(l16 << 3) + k] + dn * a[k];
      hred[wave][(l16 << 3) + k] = t >= 0.f ? t : 0.2f * t;
    }
  }
  __syncthreads();
  const int tid = threadIdx.x;
  if (tid < 128) {
    const int g0 = hg[0], g1 = hg[1], g2 = hg[2], g3 = hg[3];
    if (g0 == g1 && g1 == g2 && g2 == g3) {          // common case (sorted batch, ~312-node runs)
      const float m = fmaxf(fmaxf(hred[0][tid], hred[1][tid]), fmaxf(hred[2][tid], hred[3][tid]));
      atomicMaxF(&pooled_t[g0 * 128 + tid], m);
    } else {
      atomicMaxF(&pooled_t[g0 * 128 + tid], hred[0][tid]);
      atomicMaxF(&pooled_t[g1 * 128 + tid], hred[1][tid]);
      atomicMaxF(&pooled_t[g2 * 128 + tid], hred[2][tid]);
      atomicMaxF(&pooled_t[g3 * 128 + tid], hred[3][tid]);
    }
  }
}

// ---------------- merged FC epilogue: blocks 0..63 vision, 64..127 topo ----------------
__global__ __launch_bounds__(256) void k_fc(const float* __restrict__ pooled_v, const float* __restrict__ fcv_w,
                                            const float* __restrict__ fcv_b,
                                            const float* __restrict__ pooled_t, const float* __restrict__ fct_w,
                                            const float* __restrict__ fct_b,
                                            const float* __restrict__ inv_sigma, float* __restrict__ out) {
  const int tid = threadIdx.x;
  if (blockIdx.x < 64) {
    __shared__ f32x4 xr[128];
    const int b = blockIdx.x;
    if (tid < 128) xr[tid] = ((const f32x4*)pooled_v)[b * 128 + tid];
    __syncthreads();
    const f32x4* wr = (const f32x4*)(fcv_w + (size_t)tid * 512);
    f32x4 a4 = {0.f, 0.f, 0.f, 0.f};
    for (int f = 0; f < 128; ++f) {
      const f32x4 x = xr[f];
      const f32x4 w = wr[f];
      #pragma unroll
      for (int k = 0; k < 4; ++k) a4[k] += x[k] * w[k];
    }
    const float a = a4[0] + a4[1] + a4[2] + a4[3];
    out[b * 256 + tid] = a * inv_sigma[1] + fcv_b[tid];
  } else {
    __shared__ f32x4 xr2[32];
    const int b = blockIdx.x - 64;
    if (tid < 32) xr2[tid] = ((const f32x4*)pooled_t)[b * 32 + tid];
    __syncthreads();
    const f32x4* wr = (const f32x4*)(fct_w + (size_t)tid * 128);
    f32x4 a4 = {0.f, 0.f, 0.f, 0.f};
    for (int f = 0; f < 32; ++f) {
      const f32x4 x = xr2[f];
      const f32x4 w = wr[f];
      #pragma unroll
      for (int k = 0; k < 4; ++k) a4[k] += x[k] * w[k];
    }
    const float a = a4[0] + a4[1] + a4[2] + a4[3];
    out[NB * 256 + b * 256 + tid] = a * inv_sigma[2] + fct_b[tid];
  }
}

extern "C" void kernel_launch(void* const* d_in, const int* in_sizes, int n_in,
                              void* d_out, int out_size, void* d_ws, size_t ws_size,
                              hipStream_t stream) {
  const float* vis    = (const float*)d_in[0];
  const float* topo   = (const float*)d_in[1];
  const int*   eidx   = (const int*)d_in[2];
  const int*   batch  = (const int*)d_in[3];
  const float* conv_w = (const float*)d_in[4];
  const float* conv_b = (const float*)d_in[5];
  const float* conv_u = (const float*)d_in[6];
  const float* fcv_w  = (const float*)d_in[7];
  const float* fcv_b  = (const float*)d_in[8];
  const float* fcv_u  = (const float*)d_in[9];
  const float* gcn_w  = (const float*)d_in[10];
  const float* gcn_b  = (const float*)d_in[11];
  const float* fct_w  = (const float*)d_in[12];
  const float* fct_b  = (const float*)d_in[13];
  const float* fct_u  = (const float*)d_in[14];
  float* out = (float*)d_out;

  char* p = (char*)d_ws;
  float* inv_sigma  = (float*)p; p += 256;
  float* sn_scratch = (float*)p; p += 1796 * 4 + 240;           // v0,v1,v2,ss (pad to 16B)
  float* pooled_v   = (float*)p; p += (size_t)NB * 512 * 4;     // 131072
  float* pooled_t   = (float*)p; p += (size_t)NB * 128 * 4;     // 32768
  int*   cnt        = (int*)p;   p += (size_t)NNODE * 4;
  int*   offset     = (int*)p;   p += (size_t)NNODE * 4;
  int*   fill       = (int*)p;   p += (size_t)NNODE * 4;
  float* dis        = (float*)p; p += (size_t)NNODE * 4;
  int*   ntotal     = (int*)p;   p += 256;
  int*   sorted_src = (int*)p;   p += (size_t)NEDGE * 4;
  __bf16* xws       = (__bf16*)p; p += (size_t)NNODE * 128 * 2 + 256;
  __hip_bfloat16* Bt2 = (__hip_bfloat16*)p; p += (size_t)147456 * 2;
  p = (char*)(((uintptr_t)p + 255) & ~(uintptr_t)255);
  __bf16* visT2 = (__bf16*)p;                                   // 64 MB + tail pad (OOB-read slack)

  // init + spectral norm (parallel 3-stage)
  hipLaunchKernelGGL(k_init,    dim3(128),  dim3(256), 0, stream, pooled_v, pooled_t, cnt, fill, sn_scratch, ntotal);
  hipLaunchKernelGGL(k_sn_v,    dim3(80),   dim3(256), 0, stream, conv_w, conv_u, fcv_w, fcv_u, fct_w, fct_u, sn_scratch);
  hipLaunchKernelGGL(k_sn_w,    dim3(160),  dim3(256), 0, stream, conv_w, fcv_w, fct_w, sn_scratch);
  hipLaunchKernelGGL(k_sn_fin,  dim3(1),    dim3(256), 0, stream, sn_scratch, inv_sigma);
  // fused prep: transpose + pack + deg
  hipLaunchKernelGGL(k_prep,    dim3(4100), dim3(256), 0, stream, vis, visT2, conv_w, inv_sigma, Bt2, eidx + NEDGE, cnt);
  // scan+xw (bucket needs offset before the fused conv+bucket dispatch)
  hipLaunchKernelGGL(k_scan_xw, dim3(392),  dim3(256), 0, stream, cnt, offset, ntotal, dis, topo, gcn_w, xws);
  // vision head main + bucket overlap (conv blocks 0..1983, bucket 1984..4483)
  hipLaunchKernelGGL(k_convb,   dim3(4484), dim3(256), 0, stream, (const __hip_bfloat16*)visT2, Bt2, conv_b, pooled_v,
                     eidx, eidx + NEDGE, offset, fill, sorted_src);
  // gather (pool fused in)
  hipLaunchKernelGGL(k_gather,  dim3(5000), dim3(256), 0, stream, sorted_src, offset, cnt, dis, xws, gcn_b, batch, pooled_t);
  // merged FC epilogue (needs pooled_v + pooled_t)
  hipLaunchKernelGGL(k_fc,      dim3(128),  dim3(256), 0, stream, pooled_v, fcv_w, fcv_b, pooled_t, fct_w, fct_b, inv_sigma, out);
}